// Round 4
// baseline (861.591 us; speedup 1.0000x reference)
//
#include <hip/hip_runtime.h>
#include <math.h>

#define NNODES 65536
#define NEDGES 1048576
#define NF 32
#define EF 16
#define HD 128
#define NACT 10
#define NB 64
#define NPER 1024
#define NT 16   // nodes per tile in node-MLP kernels

__device__ __forceinline__ float leakyf(float v) { return v > 0.0f ? v : 0.01f * v; }

// 16-term dot of one edge's attributes (4 float4s) with per-lane weight column.
__device__ __forceinline__ float edge_mac16(const float4 q0, const float4 q1,
                                            const float4 q2, const float4 q3,
                                            const float* __restrict__ wr, float m)
{
    m = fmaf(q0.x, wr[0],  m); m = fmaf(q0.y, wr[1],  m);
    m = fmaf(q0.z, wr[2],  m); m = fmaf(q0.w, wr[3],  m);
    m = fmaf(q1.x, wr[4],  m); m = fmaf(q1.y, wr[5],  m);
    m = fmaf(q1.z, wr[6],  m); m = fmaf(q1.w, wr[7],  m);
    m = fmaf(q2.x, wr[8],  m); m = fmaf(q2.y, wr[9],  m);
    m = fmaf(q2.z, wr[10], m); m = fmaf(q2.w, wr[11], m);
    m = fmaf(q3.x, wr[12], m); m = fmaf(q3.y, wr[13], m);
    m = fmaf(q3.z, wr[14], m); m = fmaf(q3.w, wr[15], m);
    return m;
}

// ---------------- CSR build: histogram -> scan -> scatter(+ea permute) ----------------
__global__ __launch_bounds__(256) void hist_kernel(const int* __restrict__ ei, int* __restrict__ cnt)
{
    const int i = blockIdx.x * 256 + threadIdx.x;
    if (i < NEDGES) atomicAdd(&cnt[ei[NEDGES + i]], 1);
}

__global__ __launch_bounds__(1024) void scan_kernel(const int* __restrict__ cnt, int* __restrict__ rs)
{
    __shared__ int s[1024];
    const int t = threadIdx.x;
    int loc[64];
    int tot = 0;
    const int4* c4 = (const int4*)(cnt + t * 64);
    #pragma unroll
    for (int j = 0; j < 16; ++j) {
        const int4 v = c4[j];
        loc[4*j+0] = v.x; loc[4*j+1] = v.y; loc[4*j+2] = v.z; loc[4*j+3] = v.w;
        tot += v.x + v.y + v.z + v.w;
    }
    s[t] = tot;
    __syncthreads();
    for (int off = 1; off < 1024; off <<= 1) {
        const int v = (t >= off) ? s[t - off] : 0;
        __syncthreads();
        s[t] += v;
        __syncthreads();
    }
    int run = s[t] - tot;   // exclusive prefix
    #pragma unroll
    for (int j = 0; j < 64; ++j) { rs[t * 64 + j] = run; run += loc[j]; }
    if (t == 0) rs[NNODES] = NEDGES;
}

__global__ __launch_bounds__(256) void scatter_kernel(
    const int* __restrict__ ei, const float* __restrict__ ea,
    const int* __restrict__ rs, int* __restrict__ fill,
    int* __restrict__ ssrc, float* __restrict__ sea)
{
    const int i = blockIdx.x * 256 + threadIdx.x;
    if (i < NEDGES) {
        const int d = ei[NEDGES + i];
        const int pos = rs[d] + atomicAdd(&fill[d], 1);
        ssrc[pos] = ei[i];
        const float4* s4 = (const float4*)ea + (size_t)i * 4;
        float4*       d4 = (float4*)sea + (size_t)pos * 4;
        d4[0] = s4[0]; d4[1] = s4[1]; d4[2] = s4[2]; d4[3] = s4[3];
    }
}

// ---------------- edge layer 1 (gather): agg1[n] = sum relu(x[src] + ea@W + b) ----------------
// One wave per node. lane = (quarter q, feature-pair p): f = 2p (NF=32 -> 16 pairs),
// 4 edge chains (quarters) x 2-deep unroll = 8 edges in flight. ssrc row preloaded, shfl-broadcast.
__global__ __launch_bounds__(256) void e1_agg_kernel(
    const float* __restrict__ x, const int* __restrict__ rs,
    const int* __restrict__ ssrc, const float* __restrict__ sea,
    const float* __restrict__ w, const float* __restrict__ b, float* __restrict__ agg)
{
    const int tid  = threadIdx.x;
    const int lane = tid & 63;
    const int p    = lane & 15;
    const int f    = p * 2;
    const int q    = lane >> 4;
    const int node = blockIdx.x * 4 + (tid >> 6);
    float wr0[EF], wr1[EF];
    #pragma unroll
    for (int k = 0; k < EF; ++k) { wr0[k] = w[k * NF + f]; wr1[k] = w[k * NF + f + 1]; }
    const float b0 = b[f], b1 = b[f + 1];
    const int beg = rs[node], end = rs[node + 1];
    const int deg = end - beg;
    const int n64 = deg < 64 ? deg : 64;
    int sv = 0;
    if (lane < n64) sv = ssrc[beg + lane];
    float acc0 = 0.0f, acc1 = 0.0f;
    int j = q;
    for (; j + 4 < n64; j += 8) {   // edges j and j+4 of this quarter-chain
        const int sA = __shfl(sv, j, 64);
        const int sB = __shfl(sv, j + 4, 64);
        const float2 xA = *(const float2*)&x[(size_t)sA * NF + f];
        const float2 xB = *(const float2*)&x[(size_t)sB * NF + f];
        const float4* pA = (const float4*)sea + (size_t)(beg + j) * 4;
        const float4* pB = (const float4*)sea + (size_t)(beg + j + 4) * 4;
        const float4 A0 = pA[0], A1 = pA[1], A2 = pA[2], A3 = pA[3];
        const float4 B0 = pB[0], B1 = pB[1], B2 = pB[2], B3 = pB[3];
        const float mA0 = edge_mac16(A0, A1, A2, A3, wr0, b0);
        const float mA1 = edge_mac16(A0, A1, A2, A3, wr1, b1);
        const float mB0 = edge_mac16(B0, B1, B2, B3, wr0, b0);
        const float mB1 = edge_mac16(B0, B1, B2, B3, wr1, b1);
        acc0 += fmaxf(xA.x + mA0, 0.0f) + fmaxf(xB.x + mB0, 0.0f);
        acc1 += fmaxf(xA.y + mA1, 0.0f) + fmaxf(xB.y + mB1, 0.0f);
    }
    if (j < n64) {
        const int sA = __shfl(sv, j, 64);
        const float2 xA = *(const float2*)&x[(size_t)sA * NF + f];
        const float4* pA = (const float4*)sea + (size_t)(beg + j) * 4;
        const float4 A0 = pA[0], A1 = pA[1], A2 = pA[2], A3 = pA[3];
        const float mA0 = edge_mac16(A0, A1, A2, A3, wr0, b0);
        const float mA1 = edge_mac16(A0, A1, A2, A3, wr1, b1);
        acc0 += fmaxf(xA.x + mA0, 0.0f);
        acc1 += fmaxf(xA.y + mA1, 0.0f);
    }
    for (int e = beg + 64 + q; e < end; e += 4) {   // rare: degree > 64
        const int sA = ssrc[e];
        const float2 xA = *(const float2*)&x[(size_t)sA * NF + f];
        const float4* pA = (const float4*)sea + (size_t)e * 4;
        const float4 A0 = pA[0], A1 = pA[1], A2 = pA[2], A3 = pA[3];
        const float mA0 = edge_mac16(A0, A1, A2, A3, wr0, b0);
        const float mA1 = edge_mac16(A0, A1, A2, A3, wr1, b1);
        acc0 += fmaxf(xA.x + mA0, 0.0f);
        acc1 += fmaxf(xA.y + mA1, 0.0f);
    }
    acc0 += __shfl_xor(acc0, 16, 64); acc0 += __shfl_xor(acc0, 32, 64);
    acc1 += __shfl_xor(acc1, 16, 64); acc1 += __shfl_xor(acc1, 32, 64);
    if (lane < 16) *(float2*)&agg[(size_t)node * NF + f] = make_float2(acc0, acc1);
}

// ---------------- edge layer 2 (gather): agg2[n] = sum relu(h[src] + ea@W + b) ----------------
// One wave per node; lane owns features (2*lane, 2*lane+1). ssrc row preloaded once;
// src broadcast via readlane (scalar address), 4 independent h-gathers in flight.
__global__ __launch_bounds__(256) void e2_agg_kernel(
    const float* __restrict__ h, const int* __restrict__ rs,
    const int* __restrict__ ssrc, const float* __restrict__ sea,
    const float* __restrict__ w, const float* __restrict__ b, float* __restrict__ agg)
{
    const int tid  = threadIdx.x;
    const int lane = tid & 63;
    const int f    = lane * 2;
    const int node = blockIdx.x * 4 + (tid >> 6);
    float wr0[EF], wr1[EF];
    #pragma unroll
    for (int k = 0; k < EF; ++k) { wr0[k] = w[k * HD + f]; wr1[k] = w[k * HD + f + 1]; }
    const float b0 = b[f], b1 = b[f + 1];
    const int beg = rs[node], end = rs[node + 1];
    const int deg = end - beg;
    const int n64 = deg < 64 ? deg : 64;
    int sv = 0;
    if (lane < n64) sv = ssrc[beg + lane];
    float acc0 = 0.0f, acc1 = 0.0f;
    int j = 0;
    for (; j + 4 <= n64; j += 4) {
        const int s0 = __builtin_amdgcn_readlane(sv, j);
        const int s1 = __builtin_amdgcn_readlane(sv, j + 1);
        const int s2 = __builtin_amdgcn_readlane(sv, j + 2);
        const int s3 = __builtin_amdgcn_readlane(sv, j + 3);
        const float2 h0 = *(const float2*)&h[(size_t)s0 * HD + f];
        const float2 h1 = *(const float2*)&h[(size_t)s1 * HD + f];
        const float2 h2 = *(const float2*)&h[(size_t)s2 * HD + f];
        const float2 h3 = *(const float2*)&h[(size_t)s3 * HD + f];
        const float4* pp = (const float4*)sea + (size_t)(beg + j) * 4;
        const float4 A0 = pp[0],  A1 = pp[1],  A2 = pp[2],  A3 = pp[3];
        const float4 B0 = pp[4],  B1 = pp[5],  B2 = pp[6],  B3 = pp[7];
        const float4 C0 = pp[8],  C1 = pp[9],  C2 = pp[10], C3 = pp[11];
        const float4 D0 = pp[12], D1 = pp[13], D2 = pp[14], D3 = pp[15];
        const float m00 = edge_mac16(A0, A1, A2, A3, wr0, b0);
        const float m01 = edge_mac16(A0, A1, A2, A3, wr1, b1);
        const float m10 = edge_mac16(B0, B1, B2, B3, wr0, b0);
        const float m11 = edge_mac16(B0, B1, B2, B3, wr1, b1);
        const float m20 = edge_mac16(C0, C1, C2, C3, wr0, b0);
        const float m21 = edge_mac16(C0, C1, C2, C3, wr1, b1);
        const float m30 = edge_mac16(D0, D1, D2, D3, wr0, b0);
        const float m31 = edge_mac16(D0, D1, D2, D3, wr1, b1);
        acc0 += fmaxf(h0.x + m00, 0.0f) + fmaxf(h1.x + m10, 0.0f)
              + fmaxf(h2.x + m20, 0.0f) + fmaxf(h3.x + m30, 0.0f);
        acc1 += fmaxf(h0.y + m01, 0.0f) + fmaxf(h1.y + m11, 0.0f)
              + fmaxf(h2.y + m21, 0.0f) + fmaxf(h3.y + m31, 0.0f);
    }
    for (; j < n64; ++j) {
        const int s0 = __builtin_amdgcn_readlane(sv, j);
        const float2 h0 = *(const float2*)&h[(size_t)s0 * HD + f];
        const float4* pp = (const float4*)sea + (size_t)(beg + j) * 4;
        const float4 A0 = pp[0], A1 = pp[1], A2 = pp[2], A3 = pp[3];
        const float m00 = edge_mac16(A0, A1, A2, A3, wr0, b0);
        const float m01 = edge_mac16(A0, A1, A2, A3, wr1, b1);
        acc0 += fmaxf(h0.x + m00, 0.0f);
        acc1 += fmaxf(h0.y + m01, 0.0f);
    }
    for (int e = beg + 64; e < end; ++e) {   // rare: degree > 64
        const int s0 = ssrc[e];
        const float2 h0 = *(const float2*)&h[(size_t)s0 * HD + f];
        const float4* pp = (const float4*)sea + (size_t)e * 4;
        const float4 A0 = pp[0], A1 = pp[1], A2 = pp[2], A3 = pp[3];
        const float m00 = edge_mac16(A0, A1, A2, A3, wr0, b0);
        const float m01 = edge_mac16(A0, A1, A2, A3, wr1, b1);
        acc0 += fmaxf(h0.x + m00, 0.0f);
        acc1 += fmaxf(h0.y + m01, 0.0f);
    }
    *(float2*)&agg[(size_t)node * HD + f] = make_float2(acc0, acc1);
}

// 16-node matvec, 2 output features per lane (f, f+64): each input float4 feeds 8 FMAs,
// weight loads amortized over 16 nodes.
__device__ __forceinline__ void mv16x2(const float* __restrict__ sIn, int ld, int K,
                                       const float* __restrict__ w, float bias0, float bias1,
                                       int f, float* __restrict__ acc0, float* __restrict__ acc1)
{
    #pragma unroll
    for (int n = 0; n < NT; ++n) { acc0[n] = bias0; acc1[n] = bias1; }
    for (int k = 0; k < K; k += 4) {
        const float w00 = w[(k + 0) * HD + f],      w01 = w[(k + 1) * HD + f];
        const float w02 = w[(k + 2) * HD + f],      w03 = w[(k + 3) * HD + f];
        const float w10 = w[(k + 0) * HD + f + 64], w11 = w[(k + 1) * HD + f + 64];
        const float w12 = w[(k + 2) * HD + f + 64], w13 = w[(k + 3) * HD + f + 64];
        #pragma unroll
        for (int n = 0; n < NT; ++n) {
            const float4 iv = *(const float4*)&sIn[n * ld + k];
            acc0[n] = fmaf(iv.w, w03, fmaf(iv.z, w02, fmaf(iv.y, w01, fmaf(iv.x, w00, acc0[n]))));
            acc1[n] = fmaf(iv.w, w13, fmaf(iv.z, w12, fmaf(iv.y, w11, fmaf(iv.x, w10, acc1[n]))));
        }
    }
}

// ---------------- node MLP layer 1 (fused): h = relu(leaky((x+agg1)@w1+b1)@w2+b2) ----------------
// One wave per block, 16 nodes per tile, single in-place LDS buffer (8 KB).
__global__ __launch_bounds__(64) void n1_kernel(
    const float* __restrict__ x, const float* __restrict__ agg,
    const float* __restrict__ w1, const float* __restrict__ b1,
    const float* __restrict__ w2, const float* __restrict__ b2,
    float* __restrict__ hout)
{
    __shared__ __align__(16) float buf[NT * HD];
    const int f = threadIdx.x;
    const int tile = blockIdx.x;
    const float bias10 = b1[f], bias11 = b1[f + 64];
    const float bias20 = b2[f], bias21 = b2[f + 64];
    const size_t base = (size_t)tile * NT * NF;
    {
        const float4 xv0 = *(const float4*)&x[base + f * 4];
        const float4 av0 = *(const float4*)&agg[base + f * 4];
        *(float4*)&buf[f * 4] = make_float4(xv0.x + av0.x, xv0.y + av0.y, xv0.z + av0.z, xv0.w + av0.w);
        const float4 xv1 = *(const float4*)&x[base + 256 + f * 4];
        const float4 av1 = *(const float4*)&agg[base + 256 + f * 4];
        *(float4*)&buf[256 + f * 4] = make_float4(xv1.x + av1.x, xv1.y + av1.y, xv1.z + av1.z, xv1.w + av1.w);
    }
    __syncthreads();
    float acc0[NT], acc1[NT];
    mv16x2(buf, NF, NF, w1, bias10, bias11, f, acc0, acc1);
    __syncthreads();
    #pragma unroll
    for (int n = 0; n < NT; ++n) {
        buf[n * HD + f]      = leakyf(acc0[n]);
        buf[n * HD + f + 64] = leakyf(acc1[n]);
    }
    __syncthreads();
    mv16x2(buf, HD, HD, w2, bias20, bias21, f, acc0, acc1);
    const size_t ob = (size_t)tile * NT * HD;
    #pragma unroll
    for (int n = 0; n < NT; ++n) {
        hout[ob + n * HD + f]      = fmaxf(acc0[n], 0.0f);   // relu(leaky(z)) == relu(z)
        hout[ob + n * HD + f + 64] = fmaxf(acc1[n], 0.0f);
    }
}

// ---- node layer 2 + pooling + node-score head, all fused (h2 never leaves the CU) ----
__global__ __launch_bounds__(64) void n2_kernel(
    const float* __restrict__ h, const float* __restrict__ agg,
    const float* __restrict__ w1, const float* __restrict__ b1,
    const float* __restrict__ w2, const float* __restrict__ b2,
    const float* __restrict__ nw1, const float* __restrict__ nb1,
    const float* __restrict__ nw2, const float* __restrict__ nb2,
    const float* __restrict__ nw3, const float* __restrict__ nb3,
    float* __restrict__ pooled, float* __restrict__ scores)
{
    __shared__ __align__(16) float buf[NT * HD];
    const int f = threadIdx.x;
    const int tile = blockIdx.x;
    const float bias10  = b1[f],  bias11  = b1[f + 64];
    const float bias20  = b2[f],  bias21  = b2[f + 64];
    const float nbias10 = nb1[f], nbias11 = nb1[f + 64];
    const float nbias20 = nb2[f], nbias21 = nb2[f + 64];
    const float w3v0 = nw3[f], w3v1 = nw3[f + 64];
    const float b3v = nb3[0];
    const size_t base = (size_t)tile * NT * HD;
    #pragma unroll
    for (int jj = 0; jj < 8; ++jj) {
        const int i = (f + jj * 64) * 4;
        const float4 hv = *(const float4*)&h[base + i];
        const float4 av = *(const float4*)&agg[base + i];
        *(float4*)&buf[i] = make_float4(hv.x + av.x, hv.y + av.y, hv.z + av.z, hv.w + av.w);
    }
    __syncthreads();
    float acc0[NT], acc1[NT];
    mv16x2(buf, HD, HD, w1, bias10, bias11, f, acc0, acc1);
    __syncthreads();
    #pragma unroll
    for (int n = 0; n < NT; ++n) {
        buf[n * HD + f]      = leakyf(acc0[n]);
        buf[n * HD + f + 64] = leakyf(acc1[n]);
    }
    __syncthreads();
    mv16x2(buf, HD, HD, w2, bias20, bias21, f, acc0, acc1);
    float psum0 = 0.0f, psum1 = 0.0f;
    #pragma unroll
    for (int n = 0; n < NT; ++n) {
        acc0[n] = leakyf(acc0[n]);
        acc1[n] = leakyf(acc1[n]);
        psum0 += acc0[n];
        psum1 += acc1[n];
    }
    const int g = tile >> 6;                     // 64 tiles (16 nodes each) per graph
    atomicAdd(&pooled[g * HD + f],      psum0);
    atomicAdd(&pooled[g * HD + f + 64], psum1);
    __syncthreads();
    #pragma unroll
    for (int n = 0; n < NT; ++n) {
        buf[n * HD + f]      = acc0[n];
        buf[n * HD + f + 64] = acc1[n];
    }
    __syncthreads();
    mv16x2(buf, HD, HD, nw1, nbias10, nbias11, f, acc0, acc1);
    __syncthreads();
    #pragma unroll
    for (int n = 0; n < NT; ++n) {
        buf[n * HD + f]      = leakyf(acc0[n]);
        buf[n * HD + f + 64] = leakyf(acc1[n]);
    }
    __syncthreads();
    mv16x2(buf, HD, HD, nw2, nbias20, nbias21, f, acc0, acc1);
    float v[NT];
    #pragma unroll
    for (int n = 0; n < NT; ++n)
        v[n] = leakyf(acc0[n]) * w3v0 + leakyf(acc1[n]) * w3v1;
    #pragma unroll
    for (int off = 32; off >= 1; off >>= 1) {
        #pragma unroll
        for (int n = 0; n < NT; ++n) v[n] += __shfl_xor(v[n], off, 64);
    }
    if (f < NT) {
        const int node = tile * NT + f;
        const float s = v[f] + b3v;
        const float sc = 1.0f / (1.0f + expf(-s));
        scores[(node & 63) * NPER + (node >> 6)] = sc;   // [B, Nper] transpose
    }
}

// ---------------- action head: pooled mean -> MLP -> softmax ----------------
__global__ __launch_bounds__(128) void act_kernel(
    const float* __restrict__ pooled,
    const float* __restrict__ w1, const float* __restrict__ b1,
    const float* __restrict__ w2, const float* __restrict__ b2,
    float* __restrict__ out)
{
    __shared__ __align__(16) float p[HD];
    __shared__ float a1[HD];
    __shared__ float z[NACT];
    __shared__ float red2[2];
    const int g = blockIdx.x;
    const int tid = threadIdx.x;
    p[tid] = pooled[g * HD + tid] * (1.0f / NPER);
    __syncthreads();
    float acc = b1[tid];
    for (int k = 0; k < HD; ++k) acc = fmaf(p[k], w1[k * HD + tid], acc);
    a1[tid] = leakyf(acc);
    __syncthreads();
    if (tid < NACT) {
        float a2 = b2[tid];
        for (int k = 0; k < HD; ++k) a2 = fmaf(a1[k], w2[k * NACT + tid], a2);
        z[tid] = leakyf(a2);
    }
    __syncthreads();
    if (tid == 0) {
        float m = z[0];
        for (int i = 1; i < NACT; ++i) m = fmaxf(m, z[i]);
        red2[0] = m;
    }
    __syncthreads();
    if (tid < NACT) z[tid] = expf(z[tid] - red2[0]);
    __syncthreads();
    if (tid == 0) {
        float s = 0.0f;
        for (int i = 0; i < NACT; ++i) s += z[i];
        red2[1] = s;
    }
    __syncthreads();
    if (tid < NACT) out[g * NACT + tid] = z[tid] / red2[1];
}

extern "C" void kernel_launch(void* const* d_in, const int* in_sizes, int n_in,
                              void* d_out, int out_size, void* d_ws, size_t ws_size,
                              hipStream_t stream)
{
    const float* x    = (const float*)d_in[0];
    const int*   ei   = (const int*)d_in[1];     // int32
    const float* ea   = (const float*)d_in[2];
    const float* e1w  = (const float*)d_in[3];
    const float* e1b  = (const float*)d_in[4];
    const float* c1w1 = (const float*)d_in[5];
    const float* c1b1 = (const float*)d_in[6];
    const float* c1w2 = (const float*)d_in[7];
    const float* c1b2 = (const float*)d_in[8];
    const float* e2w  = (const float*)d_in[9];
    const float* e2b  = (const float*)d_in[10];
    const float* c2w1 = (const float*)d_in[11];
    const float* c2b1 = (const float*)d_in[12];
    const float* c2w2 = (const float*)d_in[13];
    const float* c2b2 = (const float*)d_in[14];
    const float* aw1  = (const float*)d_in[15];
    const float* ab1  = (const float*)d_in[16];
    const float* aw2  = (const float*)d_in[17];
    const float* ab2  = (const float*)d_in[18];
    const float* nw1  = (const float*)d_in[19];
    const float* nb1  = (const float*)d_in[20];
    const float* nw2  = (const float*)d_in[21];
    const float* nb2  = (const float*)d_in[22];
    const float* nw3  = (const float*)d_in[23];
    const float* nb3  = (const float*)d_in[24];

    float* out = (float*)d_out;
    char*  ws  = (char*)d_ws;
    const size_t MB = 1024 * 1024;
    // ws layout (~144 MB): h 32 | agg2 32 | sea 64 | agg1 8 | pooled | cnt | fill | rs | ssrc 4
    float* h      = (float*)(ws);
    float* agg2   = (float*)(ws + 32  * MB);
    float* sea    = (float*)(ws + 64  * MB);
    float* agg1   = (float*)(ws + 128 * MB);
    float* pooled = (float*)(ws + 136 * MB);
    int*   cnt    = (int*)  (ws + 137 * MB);
    int*   fill   = (int*)  (ws + 138 * MB);
    int*   rs     = (int*)  (ws + 139 * MB);
    int*   ssrc   = (int*)  (ws + 140 * MB);

    hipMemsetAsync(cnt,    0, NNODES * sizeof(int), stream);
    hipMemsetAsync(fill,   0, NNODES * sizeof(int), stream);
    hipMemsetAsync(pooled, 0, (size_t)NB * HD * sizeof(float), stream);

    // CSR build (dst-sorted edge permutation, edge_attr physically permuted)
    hist_kernel<<<NEDGES / 256, 256, 0, stream>>>(ei, cnt);
    scan_kernel<<<1, 1024, 0, stream>>>(cnt, rs);
    scatter_kernel<<<NEDGES / 256, 256, 0, stream>>>(ei, ea, rs, fill, ssrc, sea);

    e1_agg_kernel<<<NNODES / 4, 256, 0, stream>>>(x, rs, ssrc, sea, e1w, e1b, agg1);
    n1_kernel<<<NNODES / NT, 64, 0, stream>>>(x, agg1, c1w1, c1b1, c1w2, c1b2, h);
    e2_agg_kernel<<<NNODES / 4, 256, 0, stream>>>(h, rs, ssrc, sea, e2w, e2b, agg2);
    n2_kernel<<<NNODES / NT, 64, 0, stream>>>(h, agg2, c2w1, c2b1, c2w2, c2b2,
                                              nw1, nb1, nw2, nb2, nw3, nb3,
                                              pooled, out + NB * NACT);
    act_kernel<<<NB, 128, 0, stream>>>(pooled, aw1, ab1, aw2, ab2, out);
}

// Round 5
// 654.000 us; speedup vs baseline: 1.3174x; 1.3174x over previous
//
#include <hip/hip_runtime.h>
#include <math.h>

#define NNODES 65536
#define NEDGES 1048576
#define NF 32
#define EF 16
#define HD 128
#define NACT 10
#define NB 64
#define NPER 1024
#define NT 16   // nodes per tile in node-MLP kernels

__device__ __forceinline__ float leakyf(float v) { return v > 0.0f ? v : 0.01f * v; }

// ---------------- CSR build: histogram -> scan -> scatter(+ea permute) ----------------
__global__ __launch_bounds__(256) void hist_kernel(const int* __restrict__ ei, int* __restrict__ cnt)
{
    const int i = blockIdx.x * 256 + threadIdx.x;
    if (i < NEDGES) atomicAdd(&cnt[ei[NEDGES + i]], 1);
}

__global__ __launch_bounds__(1024) void scan_kernel(const int* __restrict__ cnt, int* __restrict__ rs)
{
    __shared__ int s[1024];
    const int t = threadIdx.x;
    int loc[64];
    int tot = 0;
    const int4* c4 = (const int4*)(cnt + t * 64);
    #pragma unroll
    for (int j = 0; j < 16; ++j) {
        const int4 v = c4[j];
        loc[4*j+0] = v.x; loc[4*j+1] = v.y; loc[4*j+2] = v.z; loc[4*j+3] = v.w;
        tot += v.x + v.y + v.z + v.w;
    }
    s[t] = tot;
    __syncthreads();
    for (int off = 1; off < 1024; off <<= 1) {
        const int v = (t >= off) ? s[t - off] : 0;
        __syncthreads();
        s[t] += v;
        __syncthreads();
    }
    int run = s[t] - tot;   // exclusive prefix
    #pragma unroll
    for (int j = 0; j < 64; ++j) { rs[t * 64 + j] = run; run += loc[j]; }
    if (t == 0) rs[NNODES] = NEDGES;
}

__global__ __launch_bounds__(256) void scatter_kernel(
    const int* __restrict__ ei, const float* __restrict__ ea,
    const int* __restrict__ rs, int* __restrict__ fill,
    int* __restrict__ ssrc, float* __restrict__ sea)
{
    const int i = blockIdx.x * 256 + threadIdx.x;
    if (i < NEDGES) {
        const int d = ei[NEDGES + i];
        const int pos = rs[d] + atomicAdd(&fill[d], 1);
        ssrc[pos] = ei[i];
        const float4* s4 = (const float4*)ea + (size_t)i * 4;
        float4*       d4 = (float4*)sea + (size_t)pos * 4;
        d4[0] = s4[0]; d4[1] = s4[1]; d4[2] = s4[2]; d4[3] = s4[3];
    }
}

// ---------------- edge layer 1 (gather): agg1[n] = sum relu(x[src] + ea@W + b) ----------------
// One wave per node; f = lane&31, two halves split the edge list; each half unrolled x2.
// (R2 version — known-good error ordering and perf.)
__global__ __launch_bounds__(256) void e1_agg_kernel(
    const float* __restrict__ x, const int* __restrict__ rs,
    const int* __restrict__ ssrc, const float* __restrict__ sea,
    const float* __restrict__ w, const float* __restrict__ b, float* __restrict__ agg)
{
    const int tid  = threadIdx.x;
    const int lane = tid & 63;
    const int f    = lane & 31;
    const int half = lane >> 5;
    const int node = blockIdx.x * 4 + (tid >> 6);
    float wr[EF];
    #pragma unroll
    for (int k = 0; k < EF; ++k) wr[k] = w[k * NF + f];
    const float bf = b[f];
    const int beg = rs[node], end = rs[node + 1];
    float acc = 0.0f;
    int e = beg + half;
    for (; e + 2 < end; e += 4) {                  // edges e and e+2 in this half-chain
        const int sA = ssrc[e], sB = ssrc[e + 2];
        const float4* pA = (const float4*)sea + (size_t)e * 4;
        const float4* pB = (const float4*)sea + (size_t)(e + 2) * 4;
        const float4 A0 = pA[0], A1 = pA[1], A2 = pA[2], A3 = pA[3];
        const float4 B0 = pB[0], B1 = pB[1], B2 = pB[2], B3 = pB[3];
        const float xA = x[(size_t)sA * NF + f];
        const float xB = x[(size_t)sB * NF + f];
        float evA[EF] = {A0.x,A0.y,A0.z,A0.w, A1.x,A1.y,A1.z,A1.w,
                         A2.x,A2.y,A2.z,A2.w, A3.x,A3.y,A3.z,A3.w};
        float evB[EF] = {B0.x,B0.y,B0.z,B0.w, B1.x,B1.y,B1.z,B1.w,
                         B2.x,B2.y,B2.z,B2.w, B3.x,B3.y,B3.z,B3.w};
        float mA = bf, mB = bf;
        #pragma unroll
        for (int k = 0; k < EF; ++k) {
            mA = fmaf(evA[k], wr[k], mA);
            mB = fmaf(evB[k], wr[k], mB);
        }
        acc += fmaxf(xA + mA, 0.0f) + fmaxf(xB + mB, 0.0f);
    }
    for (; e < end; e += 2) {
        const int sA = ssrc[e];
        const float4* pA = (const float4*)sea + (size_t)e * 4;
        const float4 A0 = pA[0], A1 = pA[1], A2 = pA[2], A3 = pA[3];
        float evA[EF] = {A0.x,A0.y,A0.z,A0.w, A1.x,A1.y,A1.z,A1.w,
                         A2.x,A2.y,A2.z,A2.w, A3.x,A3.y,A3.z,A3.w};
        float mA = bf;
        #pragma unroll
        for (int k = 0; k < EF; ++k) mA = fmaf(evA[k], wr[k], mA);
        acc += fmaxf(x[(size_t)sA * NF + f] + mA, 0.0f);
    }
    acc += __shfl_xor(acc, 32, 64);
    if (half == 0) agg[(size_t)node * NF + f] = acc;
}

// ---------------- edge layer 2 (gather): agg2[n] = sum relu(h[src] + ea@W + b) ----------------
// One wave per node; lane owns features (2*lane, 2*lane+1). beg/end forced to SGPRs via
// readfirstlane so ssrc[e] and sea[e*16+k] are wave-uniform -> compiler emits scalar
// (s_load) through the constant cache; only the h-gather uses VMEM.
__global__ __launch_bounds__(256) void e2_agg_kernel(
    const float* __restrict__ h, const int* __restrict__ rs,
    const int* __restrict__ ssrc, const float* __restrict__ sea,
    const float* __restrict__ w, const float* __restrict__ b, float* __restrict__ agg)
{
    const int tid  = threadIdx.x;
    const int lane = tid & 63;
    const int f    = lane * 2;
    const int node = blockIdx.x * 4 + (tid >> 6);
    float wr0[EF], wr1[EF];
    #pragma unroll
    for (int k = 0; k < EF; ++k) { wr0[k] = w[k * HD + f]; wr1[k] = w[k * HD + f + 1]; }
    const float b0 = b[f], b1 = b[f + 1];
    const int beg = __builtin_amdgcn_readfirstlane(rs[node]);
    const int end = __builtin_amdgcn_readfirstlane(rs[node + 1]);
    float acc0 = 0.0f, acc1 = 0.0f;
    int e = beg;
    for (; e + 2 <= end; e += 2) {
        const int sA = ssrc[e];          // uniform -> s_load
        const int sB = ssrc[e + 1];
        const float2 hA = *(const float2*)&h[(size_t)sA * HD + f];   // VMEM dwordx2, saddr
        const float2 hB = *(const float2*)&h[(size_t)sB * HD + f];
        const float* aA = &sea[(size_t)e * EF];                      // uniform -> s_load_dwordx16
        const float* aB = aA + EF;
        float mA0 = b0, mA1 = b1, mB0 = b0, mB1 = b1;
        #pragma unroll
        for (int k = 0; k < EF; ++k) {
            const float vA = aA[k];
            const float vB = aB[k];
            mA0 = fmaf(vA, wr0[k], mA0);
            mA1 = fmaf(vA, wr1[k], mA1);
            mB0 = fmaf(vB, wr0[k], mB0);
            mB1 = fmaf(vB, wr1[k], mB1);
        }
        acc0 += fmaxf(hA.x + mA0, 0.0f) + fmaxf(hB.x + mB0, 0.0f);
        acc1 += fmaxf(hA.y + mA1, 0.0f) + fmaxf(hB.y + mB1, 0.0f);
    }
    if (e < end) {
        const int sA = ssrc[e];
        const float2 hA = *(const float2*)&h[(size_t)sA * HD + f];
        const float* aA = &sea[(size_t)e * EF];
        float mA0 = b0, mA1 = b1;
        #pragma unroll
        for (int k = 0; k < EF; ++k) {
            const float vA = aA[k];
            mA0 = fmaf(vA, wr0[k], mA0);
            mA1 = fmaf(vA, wr1[k], mA1);
        }
        acc0 += fmaxf(hA.x + mA0, 0.0f);
        acc1 += fmaxf(hA.y + mA1, 0.0f);
    }
    *(float2*)&agg[(size_t)node * HD + f] = make_float2(acc0, acc1);
}

// 16-node matvec, 2 output features per lane (f, f+64): each input float4 feeds 8 FMAs,
// weight loads amortized over 16 nodes.
__device__ __forceinline__ void mv16x2(const float* __restrict__ sIn, int ld, int K,
                                       const float* __restrict__ w, float bias0, float bias1,
                                       int f, float* __restrict__ acc0, float* __restrict__ acc1)
{
    #pragma unroll
    for (int n = 0; n < NT; ++n) { acc0[n] = bias0; acc1[n] = bias1; }
    for (int k = 0; k < K; k += 4) {
        const float w00 = w[(k + 0) * HD + f],      w01 = w[(k + 1) * HD + f];
        const float w02 = w[(k + 2) * HD + f],      w03 = w[(k + 3) * HD + f];
        const float w10 = w[(k + 0) * HD + f + 64], w11 = w[(k + 1) * HD + f + 64];
        const float w12 = w[(k + 2) * HD + f + 64], w13 = w[(k + 3) * HD + f + 64];
        #pragma unroll
        for (int n = 0; n < NT; ++n) {
            const float4 iv = *(const float4*)&sIn[n * ld + k];
            acc0[n] = fmaf(iv.w, w03, fmaf(iv.z, w02, fmaf(iv.y, w01, fmaf(iv.x, w00, acc0[n]))));
            acc1[n] = fmaf(iv.w, w13, fmaf(iv.z, w12, fmaf(iv.y, w11, fmaf(iv.x, w10, acc1[n]))));
        }
    }
}

// ---------------- node MLP layer 1 (fused): h = relu(leaky((x+agg1)@w1+b1)@w2+b2) ----------------
// One wave per block, 16 nodes per tile, single in-place LDS buffer (8 KB).
__global__ __launch_bounds__(64) void n1_kernel(
    const float* __restrict__ x, const float* __restrict__ agg,
    const float* __restrict__ w1, const float* __restrict__ b1,
    const float* __restrict__ w2, const float* __restrict__ b2,
    float* __restrict__ hout)
{
    __shared__ __align__(16) float buf[NT * HD];
    const int f = threadIdx.x;
    const int tile = blockIdx.x;
    const float bias10 = b1[f], bias11 = b1[f + 64];
    const float bias20 = b2[f], bias21 = b2[f + 64];
    const size_t base = (size_t)tile * NT * NF;
    {
        const float4 xv0 = *(const float4*)&x[base + f * 4];
        const float4 av0 = *(const float4*)&agg[base + f * 4];
        *(float4*)&buf[f * 4] = make_float4(xv0.x + av0.x, xv0.y + av0.y, xv0.z + av0.z, xv0.w + av0.w);
        const float4 xv1 = *(const float4*)&x[base + 256 + f * 4];
        const float4 av1 = *(const float4*)&agg[base + 256 + f * 4];
        *(float4*)&buf[256 + f * 4] = make_float4(xv1.x + av1.x, xv1.y + av1.y, xv1.z + av1.z, xv1.w + av1.w);
    }
    __syncthreads();
    float acc0[NT], acc1[NT];
    mv16x2(buf, NF, NF, w1, bias10, bias11, f, acc0, acc1);
    __syncthreads();
    #pragma unroll
    for (int n = 0; n < NT; ++n) {
        buf[n * HD + f]      = leakyf(acc0[n]);
        buf[n * HD + f + 64] = leakyf(acc1[n]);
    }
    __syncthreads();
    mv16x2(buf, HD, HD, w2, bias20, bias21, f, acc0, acc1);
    const size_t ob = (size_t)tile * NT * HD;
    #pragma unroll
    for (int n = 0; n < NT; ++n) {
        hout[ob + n * HD + f]      = fmaxf(acc0[n], 0.0f);   // relu(leaky(z)) == relu(z)
        hout[ob + n * HD + f + 64] = fmaxf(acc1[n], 0.0f);
    }
}

// ---- node layer 2 + pooling + node-score head, all fused (h2 never leaves the CU) ----
__global__ __launch_bounds__(64) void n2_kernel(
    const float* __restrict__ h, const float* __restrict__ agg,
    const float* __restrict__ w1, const float* __restrict__ b1,
    const float* __restrict__ w2, const float* __restrict__ b2,
    const float* __restrict__ nw1, const float* __restrict__ nb1,
    const float* __restrict__ nw2, const float* __restrict__ nb2,
    const float* __restrict__ nw3, const float* __restrict__ nb3,
    float* __restrict__ pooled, float* __restrict__ scores)
{
    __shared__ __align__(16) float buf[NT * HD];
    const int f = threadIdx.x;
    const int tile = blockIdx.x;
    const float bias10  = b1[f],  bias11  = b1[f + 64];
    const float bias20  = b2[f],  bias21  = b2[f + 64];
    const float nbias10 = nb1[f], nbias11 = nb1[f + 64];
    const float nbias20 = nb2[f], nbias21 = nb2[f + 64];
    const float w3v0 = nw3[f], w3v1 = nw3[f + 64];
    const float b3v = nb3[0];
    const size_t base = (size_t)tile * NT * HD;
    #pragma unroll
    for (int jj = 0; jj < 8; ++jj) {
        const int i = (f + jj * 64) * 4;
        const float4 hv = *(const float4*)&h[base + i];
        const float4 av = *(const float4*)&agg[base + i];
        *(float4*)&buf[i] = make_float4(hv.x + av.x, hv.y + av.y, hv.z + av.z, hv.w + av.w);
    }
    __syncthreads();
    float acc0[NT], acc1[NT];
    mv16x2(buf, HD, HD, w1, bias10, bias11, f, acc0, acc1);
    __syncthreads();
    #pragma unroll
    for (int n = 0; n < NT; ++n) {
        buf[n * HD + f]      = leakyf(acc0[n]);
        buf[n * HD + f + 64] = leakyf(acc1[n]);
    }
    __syncthreads();
    mv16x2(buf, HD, HD, w2, bias20, bias21, f, acc0, acc1);
    float psum0 = 0.0f, psum1 = 0.0f;
    #pragma unroll
    for (int n = 0; n < NT; ++n) {
        acc0[n] = leakyf(acc0[n]);
        acc1[n] = leakyf(acc1[n]);
        psum0 += acc0[n];
        psum1 += acc1[n];
    }
    const int g = tile >> 6;                     // 64 tiles (16 nodes each) per graph
    atomicAdd(&pooled[g * HD + f],      psum0);
    atomicAdd(&pooled[g * HD + f + 64], psum1);
    __syncthreads();
    #pragma unroll
    for (int n = 0; n < NT; ++n) {
        buf[n * HD + f]      = acc0[n];
        buf[n * HD + f + 64] = acc1[n];
    }
    __syncthreads();
    mv16x2(buf, HD, HD, nw1, nbias10, nbias11, f, acc0, acc1);
    __syncthreads();
    #pragma unroll
    for (int n = 0; n < NT; ++n) {
        buf[n * HD + f]      = leakyf(acc0[n]);
        buf[n * HD + f + 64] = leakyf(acc1[n]);
    }
    __syncthreads();
    mv16x2(buf, HD, HD, nw2, nbias20, nbias21, f, acc0, acc1);
    float v[NT];
    #pragma unroll
    for (int n = 0; n < NT; ++n)
        v[n] = leakyf(acc0[n]) * w3v0 + leakyf(acc1[n]) * w3v1;
    #pragma unroll
    for (int off = 32; off >= 1; off >>= 1) {
        #pragma unroll
        for (int n = 0; n < NT; ++n) v[n] += __shfl_xor(v[n], off, 64);
    }
    if (f < NT) {
        const int node = tile * NT + f;
        const float s = v[f] + b3v;
        const float sc = 1.0f / (1.0f + expf(-s));
        scores[(node & 63) * NPER + (node >> 6)] = sc;   // [B, Nper] transpose
    }
}

// ---------------- action head: pooled mean -> MLP -> softmax ----------------
__global__ __launch_bounds__(128) void act_kernel(
    const float* __restrict__ pooled,
    const float* __restrict__ w1, const float* __restrict__ b1,
    const float* __restrict__ w2, const float* __restrict__ b2,
    float* __restrict__ out)
{
    __shared__ __align__(16) float p[HD];
    __shared__ float a1[HD];
    __shared__ float z[NACT];
    __shared__ float red2[2];
    const int g = blockIdx.x;
    const int tid = threadIdx.x;
    p[tid] = pooled[g * HD + tid] * (1.0f / NPER);
    __syncthreads();
    float acc = b1[tid];
    for (int k = 0; k < HD; ++k) acc = fmaf(p[k], w1[k * HD + tid], acc);
    a1[tid] = leakyf(acc);
    __syncthreads();
    if (tid < NACT) {
        float a2 = b2[tid];
        for (int k = 0; k < HD; ++k) a2 = fmaf(a1[k], w2[k * NACT + tid], a2);
        z[tid] = leakyf(a2);
    }
    __syncthreads();
    if (tid == 0) {
        float m = z[0];
        for (int i = 1; i < NACT; ++i) m = fmaxf(m, z[i]);
        red2[0] = m;
    }
    __syncthreads();
    if (tid < NACT) z[tid] = expf(z[tid] - red2[0]);
    __syncthreads();
    if (tid == 0) {
        float s = 0.0f;
        for (int i = 0; i < NACT; ++i) s += z[i];
        red2[1] = s;
    }
    __syncthreads();
    if (tid < NACT) out[g * NACT + tid] = z[tid] / red2[1];
}

extern "C" void kernel_launch(void* const* d_in, const int* in_sizes, int n_in,
                              void* d_out, int out_size, void* d_ws, size_t ws_size,
                              hipStream_t stream)
{
    const float* x    = (const float*)d_in[0];
    const int*   ei   = (const int*)d_in[1];     // int32
    const float* ea   = (const float*)d_in[2];
    const float* e1w  = (const float*)d_in[3];
    const float* e1b  = (const float*)d_in[4];
    const float* c1w1 = (const float*)d_in[5];
    const float* c1b1 = (const float*)d_in[6];
    const float* c1w2 = (const float*)d_in[7];
    const float* c1b2 = (const float*)d_in[8];
    const float* e2w  = (const float*)d_in[9];
    const float* e2b  = (const float*)d_in[10];
    const float* c2w1 = (const float*)d_in[11];
    const float* c2b1 = (const float*)d_in[12];
    const float* c2w2 = (const float*)d_in[13];
    const float* c2b2 = (const float*)d_in[14];
    const float* aw1  = (const float*)d_in[15];
    const float* ab1  = (const float*)d_in[16];
    const float* aw2  = (const float*)d_in[17];
    const float* ab2  = (const float*)d_in[18];
    const float* nw1  = (const float*)d_in[19];
    const float* nb1  = (const float*)d_in[20];
    const float* nw2  = (const float*)d_in[21];
    const float* nb2  = (const float*)d_in[22];
    const float* nw3  = (const float*)d_in[23];
    const float* nb3  = (const float*)d_in[24];

    float* out = (float*)d_out;
    char*  ws  = (char*)d_ws;
    const size_t MB = 1024 * 1024;
    // ws layout (~144 MB): h 32 | agg2 32 | sea 64 | agg1 8 | pooled | cnt | fill | rs | ssrc 4
    float* h      = (float*)(ws);
    float* agg2   = (float*)(ws + 32  * MB);
    float* sea    = (float*)(ws + 64  * MB);
    float* agg1   = (float*)(ws + 128 * MB);
    float* pooled = (float*)(ws + 136 * MB);
    int*   cnt    = (int*)  (ws + 137 * MB);
    int*   fill   = (int*)  (ws + 138 * MB);
    int*   rs     = (int*)  (ws + 139 * MB);
    int*   ssrc   = (int*)  (ws + 140 * MB);

    hipMemsetAsync(cnt,    0, NNODES * sizeof(int), stream);
    hipMemsetAsync(fill,   0, NNODES * sizeof(int), stream);
    hipMemsetAsync(pooled, 0, (size_t)NB * HD * sizeof(float), stream);

    // CSR build (dst-sorted edge permutation, edge_attr physically permuted)
    hist_kernel<<<NEDGES / 256, 256, 0, stream>>>(ei, cnt);
    scan_kernel<<<1, 1024, 0, stream>>>(cnt, rs);
    scatter_kernel<<<NEDGES / 256, 256, 0, stream>>>(ei, ea, rs, fill, ssrc, sea);

    e1_agg_kernel<<<NNODES / 4, 256, 0, stream>>>(x, rs, ssrc, sea, e1w, e1b, agg1);
    n1_kernel<<<NNODES / NT, 64, 0, stream>>>(x, agg1, c1w1, c1b1, c1w2, c1b2, h);
    e2_agg_kernel<<<NNODES / 4, 256, 0, stream>>>(h, rs, ssrc, sea, e2w, e2b, agg2);
    n2_kernel<<<NNODES / NT, 64, 0, stream>>>(h, agg2, c2w1, c2b1, c2w2, c2b2,
                                              nw1, nb1, nw2, nb2, nw3, nb3,
                                              pooled, out + NB * NACT);
    act_kernel<<<NB, 128, 0, stream>>>(pooled, aw1, ab1, aw2, ab2, out);
}

// Round 6
// 591.220 us; speedup vs baseline: 1.4573x; 1.1062x over previous
//
#include <hip/hip_runtime.h>
#include <math.h>

#define NNODES 65536
#define NEDGES 1048576
#define NF 32
#define EF 16
#define HD 128
#define NACT 10
#define NB 64
#define NPER 1024

typedef unsigned short u16;
typedef float  vf4  __attribute__((ext_vector_type(4)));
typedef __bf16 vbf8 __attribute__((ext_vector_type(8)));
#define BC8(v) __builtin_bit_cast(vbf8, v)

__device__ __forceinline__ float leakyf(float v) { return v > 0.0f ? v : 0.01f * v; }

__device__ __forceinline__ u16 f2bf(float x) {
    unsigned u = __float_as_uint(x);
    return (u16)((u + 0x7FFFu + ((u >> 16) & 1u)) >> 16);
}
__device__ __forceinline__ float bf2f(u16 h) { return __uint_as_float(((unsigned)h) << 16); }

// split f32x4 into bf16-hi and bf16-lo packed pairs (hi + lo ~= full f32 precision)
__device__ __forceinline__ void cvt4(const float4 s, uint2& hi, uint2& lo) {
    const u16 h0 = f2bf(s.x), h1 = f2bf(s.y), h2 = f2bf(s.z), h3 = f2bf(s.w);
    hi = make_uint2((unsigned)h0 | ((unsigned)h1 << 16), (unsigned)h2 | ((unsigned)h3 << 16));
    const u16 l0 = f2bf(s.x - bf2f(h0)), l1 = f2bf(s.y - bf2f(h1));
    const u16 l2 = f2bf(s.z - bf2f(h2)), l3 = f2bf(s.w - bf2f(h3));
    lo = make_uint2((unsigned)l0 | ((unsigned)l1 << 16), (unsigned)l2 | ((unsigned)l3 << 16));
}

// ---------------- CSR build: histogram -> scan -> scatter(+ea permute) ----------------
__global__ __launch_bounds__(256) void hist_kernel(const int* __restrict__ ei, int* __restrict__ cnt)
{
    const int i = blockIdx.x * 256 + threadIdx.x;
    if (i < NEDGES) atomicAdd(&cnt[ei[NEDGES + i]], 1);
}

__global__ __launch_bounds__(1024) void scan_kernel(const int* __restrict__ cnt, int* __restrict__ rs)
{
    __shared__ int s[1024];
    const int t = threadIdx.x;
    int loc[64];
    int tot = 0;
    const int4* c4 = (const int4*)(cnt + t * 64);
    #pragma unroll
    for (int j = 0; j < 16; ++j) {
        const int4 v = c4[j];
        loc[4*j+0] = v.x; loc[4*j+1] = v.y; loc[4*j+2] = v.z; loc[4*j+3] = v.w;
        tot += v.x + v.y + v.z + v.w;
    }
    s[t] = tot;
    __syncthreads();
    for (int off = 1; off < 1024; off <<= 1) {
        const int v = (t >= off) ? s[t - off] : 0;
        __syncthreads();
        s[t] += v;
        __syncthreads();
    }
    int run = s[t] - tot;
    #pragma unroll
    for (int j = 0; j < 64; ++j) { rs[t * 64 + j] = run; run += loc[j]; }
    if (t == 0) rs[NNODES] = NEDGES;
}

__global__ __launch_bounds__(256) void scatter_kernel(
    const int* __restrict__ ei, const float* __restrict__ ea,
    const int* __restrict__ rs, int* __restrict__ fill,
    int* __restrict__ ssrc, float* __restrict__ sea)
{
    const int i = blockIdx.x * 256 + threadIdx.x;
    if (i < NEDGES) {
        const int d = ei[NEDGES + i];
        const int pos = rs[d] + atomicAdd(&fill[d], 1);
        ssrc[pos] = ei[i];
        const float4* s4 = (const float4*)ea + (size_t)i * 4;
        float4*       d4 = (float4*)sea + (size_t)pos * 4;
        d4[0] = s4[0]; d4[1] = s4[1]; d4[2] = s4[2]; d4[3] = s4[3];
    }
}

// ---------------- weight packing: W[K][128] -> MFMA A-fragment order, bf16 hi/lo ----------------
// A-frag element for (fb, kb, lane, j): W[kb*32 + (lane>>4)*8 + j][fb*16 + (lane&15)]
__global__ __launch_bounds__(256) void pack_w_kernel(
    const float* __restrict__ W, int KB, u16* __restrict__ hi, u16* __restrict__ lo)
{
    const int t = blockIdx.x * 256 + threadIdx.x;
    const int j = t & 7, lane = (t >> 3) & 63, rest = t >> 9;
    const int kb = rest % KB, fb = rest / KB;
    if (fb >= 8) return;
    const int k = kb * 32 + (lane >> 4) * 8 + j;
    const int f = fb * 16 + (lane & 15);
    const float val = W[k * HD + f];
    const u16 h = f2bf(val);
    hi[t] = h;
    lo[t] = f2bf(val - bf2f(h));
}

// ---------------- edge layer 1 (gather) — R2-proven version ----------------
__global__ __launch_bounds__(256) void e1_agg_kernel(
    const float* __restrict__ x, const int* __restrict__ rs,
    const int* __restrict__ ssrc, const float* __restrict__ sea,
    const float* __restrict__ w, const float* __restrict__ b, float* __restrict__ agg)
{
    const int tid  = threadIdx.x;
    const int lane = tid & 63;
    const int f    = lane & 31;
    const int half = lane >> 5;
    const int node = blockIdx.x * 4 + (tid >> 6);
    float wr[EF];
    #pragma unroll
    for (int k = 0; k < EF; ++k) wr[k] = w[k * NF + f];
    const float bf = b[f];
    const int beg = rs[node], end = rs[node + 1];
    float acc = 0.0f;
    int e = beg + half;
    for (; e + 2 < end; e += 4) {
        const int sA = ssrc[e], sB = ssrc[e + 2];
        const float4* pA = (const float4*)sea + (size_t)e * 4;
        const float4* pB = (const float4*)sea + (size_t)(e + 2) * 4;
        const float4 A0 = pA[0], A1 = pA[1], A2 = pA[2], A3 = pA[3];
        const float4 B0 = pB[0], B1 = pB[1], B2 = pB[2], B3 = pB[3];
        const float xA = x[(size_t)sA * NF + f];
        const float xB = x[(size_t)sB * NF + f];
        float evA[EF] = {A0.x,A0.y,A0.z,A0.w, A1.x,A1.y,A1.z,A1.w,
                         A2.x,A2.y,A2.z,A2.w, A3.x,A3.y,A3.z,A3.w};
        float evB[EF] = {B0.x,B0.y,B0.z,B0.w, B1.x,B1.y,B1.z,B1.w,
                         B2.x,B2.y,B2.z,B2.w, B3.x,B3.y,B3.z,B3.w};
        float mA = bf, mB = bf;
        #pragma unroll
        for (int k = 0; k < EF; ++k) {
            mA = fmaf(evA[k], wr[k], mA);
            mB = fmaf(evB[k], wr[k], mB);
        }
        acc += fmaxf(xA + mA, 0.0f) + fmaxf(xB + mB, 0.0f);
    }
    for (; e < end; e += 2) {
        const int sA = ssrc[e];
        const float4* pA = (const float4*)sea + (size_t)e * 4;
        const float4 A0 = pA[0], A1 = pA[1], A2 = pA[2], A3 = pA[3];
        float evA[EF] = {A0.x,A0.y,A0.z,A0.w, A1.x,A1.y,A1.z,A1.w,
                         A2.x,A2.y,A2.z,A2.w, A3.x,A3.y,A3.z,A3.w};
        float mA = bf;
        #pragma unroll
        for (int k = 0; k < EF; ++k) mA = fmaf(evA[k], wr[k], mA);
        acc += fmaxf(x[(size_t)sA * NF + f] + mA, 0.0f);
    }
    acc += __shfl_xor(acc, 32, 64);
    if (half == 0) agg[(size_t)node * NF + f] = acc;
}

// ---------------- edge layer 2 (gather) — scalar-uniform version ----------------
__global__ __launch_bounds__(256) void e2_agg_kernel(
    const float* __restrict__ h, const int* __restrict__ rs,
    const int* __restrict__ ssrc, const float* __restrict__ sea,
    const float* __restrict__ w, const float* __restrict__ b, float* __restrict__ agg)
{
    const int tid  = threadIdx.x;
    const int lane = tid & 63;
    const int f    = lane * 2;
    const int node = blockIdx.x * 4 + (tid >> 6);
    float wr0[EF], wr1[EF];
    #pragma unroll
    for (int k = 0; k < EF; ++k) { wr0[k] = w[k * HD + f]; wr1[k] = w[k * HD + f + 1]; }
    const float b0 = b[f], b1 = b[f + 1];
    const int beg = __builtin_amdgcn_readfirstlane(rs[node]);
    const int end = __builtin_amdgcn_readfirstlane(rs[node + 1]);
    float acc0 = 0.0f, acc1 = 0.0f;
    int e = beg;
    for (; e + 2 <= end; e += 2) {
        const int sA = ssrc[e];
        const int sB = ssrc[e + 1];
        const float2 hA = *(const float2*)&h[(size_t)sA * HD + f];
        const float2 hB = *(const float2*)&h[(size_t)sB * HD + f];
        const float* aA = &sea[(size_t)e * EF];
        const float* aB = aA + EF;
        float mA0 = b0, mA1 = b1, mB0 = b0, mB1 = b1;
        #pragma unroll
        for (int k = 0; k < EF; ++k) {
            const float vA = aA[k];
            const float vB = aB[k];
            mA0 = fmaf(vA, wr0[k], mA0);
            mA1 = fmaf(vA, wr1[k], mA1);
            mB0 = fmaf(vB, wr0[k], mB0);
            mB1 = fmaf(vB, wr1[k], mB1);
        }
        acc0 += fmaxf(hA.x + mA0, 0.0f) + fmaxf(hB.x + mB0, 0.0f);
        acc1 += fmaxf(hA.y + mA1, 0.0f) + fmaxf(hB.y + mB1, 0.0f);
    }
    if (e < end) {
        const int sA = ssrc[e];
        const float2 hA = *(const float2*)&h[(size_t)sA * HD + f];
        const float* aA = &sea[(size_t)e * EF];
        float mA0 = b0, mA1 = b1;
        #pragma unroll
        for (int k = 0; k < EF; ++k) {
            const float vA = aA[k];
            mA0 = fmaf(vA, wr0[k], mA0);
            mA1 = fmaf(vA, wr1[k], mA1);
        }
        acc0 += fmaxf(hA.x + mA0, 0.0f);
        acc1 += fmaxf(hA.y + mA1, 0.0f);
    }
    *(float2*)&agg[(size_t)node * HD + f] = make_float2(acc0, acc1);
}

// ---------------- MFMA node-GEMM building blocks ----------------
// Activations in LDS: bf16 rows [16 nodes][row of K], row stride padded to 16B mult.
// D[f][node] = sum_k W[k][f] * in[node][k]; A-frag = packed weights, B-frag = act rows.
// split product: hi*lo + lo*hi + hi*hi accumulated in f32.

#define ROW128 272   // 128 bf16 = 256 B + 16 pad
#define ROW32  80    // 32 bf16 = 64 B + 16 pad

__device__ __forceinline__ void mfma_layer128(
    const unsigned char* __restrict__ aH, const unsigned char* __restrict__ aL,
    const u16* __restrict__ wH, const u16* __restrict__ wL,
    const float* __restrict__ bias, int lane, vf4* __restrict__ acc)
{
    const int quad = lane >> 4, fm = lane & 15;
    int4 Bh[4], Bl[4];
    #pragma unroll
    for (int kb = 0; kb < 4; ++kb) {
        Bh[kb] = *(const int4*)(aH + fm * ROW128 + kb * 64 + quad * 16);
        Bl[kb] = *(const int4*)(aL + fm * ROW128 + kb * 64 + quad * 16);
    }
    #pragma unroll
    for (int fb = 0; fb < 8; ++fb) {
        const float4 bv = *(const float4*)&bias[fb * 16 + quad * 4];
        vf4 a = {bv.x, bv.y, bv.z, bv.w};
        #pragma unroll
        for (int kb = 0; kb < 4; ++kb) {
            const int4 wh = *(const int4*)(wH + ((fb * 4 + kb) * 64 + lane) * 8);
            const int4 wl = *(const int4*)(wL + ((fb * 4 + kb) * 64 + lane) * 8);
            a = __builtin_amdgcn_mfma_f32_16x16x32_bf16(BC8(wh), BC8(Bl[kb]), a, 0, 0, 0);
            a = __builtin_amdgcn_mfma_f32_16x16x32_bf16(BC8(wl), BC8(Bh[kb]), a, 0, 0, 0);
            a = __builtin_amdgcn_mfma_f32_16x16x32_bf16(BC8(wh), BC8(Bh[kb]), a, 0, 0, 0);
        }
        acc[fb] = a;
    }
}

__device__ __forceinline__ void mfma_layer32(
    const unsigned char* __restrict__ aH, const unsigned char* __restrict__ aL,
    const u16* __restrict__ wH, const u16* __restrict__ wL,
    const float* __restrict__ bias, int lane, vf4* __restrict__ acc)
{
    const int quad = lane >> 4, fm = lane & 15;
    const int4 Bh = *(const int4*)(aH + fm * ROW32 + quad * 16);
    const int4 Bl = *(const int4*)(aL + fm * ROW32 + quad * 16);
    #pragma unroll
    for (int fb = 0; fb < 8; ++fb) {
        const float4 bv = *(const float4*)&bias[fb * 16 + quad * 4];
        vf4 a = {bv.x, bv.y, bv.z, bv.w};
        const int4 wh = *(const int4*)(wH + (fb * 64 + lane) * 8);
        const int4 wl = *(const int4*)(wL + (fb * 64 + lane) * 8);
        a = __builtin_amdgcn_mfma_f32_16x16x32_bf16(BC8(wh), BC8(Bl), a, 0, 0, 0);
        a = __builtin_amdgcn_mfma_f32_16x16x32_bf16(BC8(wl), BC8(Bh), a, 0, 0, 0);
        a = __builtin_amdgcn_mfma_f32_16x16x32_bf16(BC8(wh), BC8(Bh), a, 0, 0, 0);
        acc[fb] = a;
    }
}

// apply leaky, write activations back to LDS rows (acc updated to post-activation values)
__device__ __forceinline__ void store_act_leaky(
    unsigned char* __restrict__ aH, unsigned char* __restrict__ aL, int lane, vf4* __restrict__ acc)
{
    const int quad = lane >> 4, fm = lane & 15;
    #pragma unroll
    for (int fb = 0; fb < 8; ++fb) {
        const float4 s = {leakyf(acc[fb][0]), leakyf(acc[fb][1]), leakyf(acc[fb][2]), leakyf(acc[fb][3])};
        acc[fb][0] = s.x; acc[fb][1] = s.y; acc[fb][2] = s.z; acc[fb][3] = s.w;
        uint2 phi, plo;
        cvt4(s, phi, plo);
        *(uint2*)(aH + fm * ROW128 + fb * 32 + quad * 8) = phi;
        *(uint2*)(aL + fm * ROW128 + fb * 32 + quad * 8) = plo;
    }
}

// ---------------- node MLP layer 1 (MFMA): h = relu((x+agg1)@w1 -> leaky -> @w2) ----------------
__global__ __launch_bounds__(256) void n1_kernel(
    const float* __restrict__ x, const float* __restrict__ agg,
    const u16* __restrict__ w1h, const u16* __restrict__ w1l, const float* __restrict__ b1,
    const u16* __restrict__ w2h, const u16* __restrict__ w2l, const float* __restrict__ b2,
    float* __restrict__ hout)
{
    __shared__ __align__(16) unsigned char smem[4][2560 + 2 * 16 * ROW128];
    const int tid = threadIdx.x, lane = tid & 63, wid = tid >> 6;
    const int quad = lane >> 4, fm = lane & 15;
    const int tile = blockIdx.x * 4 + wid;
    unsigned char* inH = smem[wid];                 // 16 x ROW32
    unsigned char* inL = inH + 16 * ROW32;
    unsigned char* aH  = inH + 2560;                // 16 x ROW128
    unsigned char* aL  = aH + 16 * ROW128;
    const size_t base = (size_t)tile * 16 * NF;
    #pragma unroll
    for (int i = 0; i < 2; ++i) {
        const int flat = i * 64 + lane;             // float4 id
        const int node = flat >> 3, kq = flat & 7;
        const float4 xv = *(const float4*)&x[base + node * NF + kq * 4];
        const float4 av = *(const float4*)&agg[base + node * NF + kq * 4];
        const float4 s = {xv.x + av.x, xv.y + av.y, xv.z + av.z, xv.w + av.w};
        uint2 phi, plo;
        cvt4(s, phi, plo);
        *(uint2*)(inH + node * ROW32 + kq * 8) = phi;
        *(uint2*)(inL + node * ROW32 + kq * 8) = plo;
    }
    __syncthreads();
    vf4 acc[8];
    mfma_layer32(inH, inL, w1h, w1l, b1, lane, acc);
    __syncthreads();
    store_act_leaky(aH, aL, lane, acc);
    __syncthreads();
    mfma_layer128(aH, aL, w2h, w2l, b2, lane, acc);
    const size_t ob = (size_t)tile * 16 * HD;
    #pragma unroll
    for (int fb = 0; fb < 8; ++fb) {
        const float4 o = {fmaxf(acc[fb][0], 0.0f), fmaxf(acc[fb][1], 0.0f),
                          fmaxf(acc[fb][2], 0.0f), fmaxf(acc[fb][3], 0.0f)};
        *(float4*)&hout[ob + fm * HD + fb * 16 + quad * 4] = o;   // relu(leaky(z)) == relu(z)
    }
}

// ---- node layer 2 + pooling + node-score head (MFMA, h2 never leaves the CU) ----
__global__ __launch_bounds__(256) void n2_kernel(
    const float* __restrict__ h, const float* __restrict__ agg,
    const u16* __restrict__ w1h, const u16* __restrict__ w1l, const float* __restrict__ b1,
    const u16* __restrict__ w2h, const u16* __restrict__ w2l, const float* __restrict__ b2,
    const u16* __restrict__ m1h, const u16* __restrict__ m1l, const float* __restrict__ nb1,
    const u16* __restrict__ m2h, const u16* __restrict__ m2l, const float* __restrict__ nb2,
    const float* __restrict__ nw3, const float* __restrict__ nb3,
    float* __restrict__ pooled, float* __restrict__ scores)
{
    __shared__ __align__(16) unsigned char smem[4][2 * 16 * ROW128];
    const int tid = threadIdx.x, lane = tid & 63, wid = tid >> 6;
    const int quad = lane >> 4, fm = lane & 15;
    const int tile = blockIdx.x * 4 + wid;
    unsigned char* aH = smem[wid];
    unsigned char* aL = aH + 16 * ROW128;
    const size_t base = (size_t)tile * 16 * HD;
    #pragma unroll
    for (int i = 0; i < 8; ++i) {
        const int flat = i * 64 + lane;
        const int node = flat >> 5, kq = flat & 31;
        const float4 hv = *(const float4*)&h[base + node * HD + kq * 4];
        const float4 av = *(const float4*)&agg[base + node * HD + kq * 4];
        const float4 s = {hv.x + av.x, hv.y + av.y, hv.z + av.z, hv.w + av.w};
        uint2 phi, plo;
        cvt4(s, phi, plo);
        *(uint2*)(aH + node * ROW128 + kq * 8) = phi;
        *(uint2*)(aL + node * ROW128 + kq * 8) = plo;
    }
    __syncthreads();
    vf4 acc[8];
    // conv2 layer 1
    mfma_layer128(aH, aL, w1h, w1l, b1, lane, acc);
    __syncthreads();
    store_act_leaky(aH, aL, lane, acc);
    __syncthreads();
    // conv2 layer 2 -> h2
    mfma_layer128(aH, aL, w2h, w2l, b2, lane, acc);
    __syncthreads();
    store_act_leaky(aH, aL, lane, acc);          // acc now holds h2 (leaky'd)
    // pooling: reduce over the 16 node-lanes, then predicated atomics (static indices)
    {
        const int g = tile >> 6;                 // 64 tiles of 16 nodes per graph
        #pragma unroll
        for (int fb = 0; fb < 8; ++fb) {
            vf4 t = acc[fb];
            #pragma unroll
            for (int off = 1; off < 16; off <<= 1) {
                t[0] += __shfl_xor(t[0], off, 64);
                t[1] += __shfl_xor(t[1], off, 64);
                t[2] += __shfl_xor(t[2], off, 64);
                t[3] += __shfl_xor(t[3], off, 64);
            }
            #pragma unroll
            for (int r = 0; r < 4; ++r) {
                const int item = fb * 4 + r;     // 0..31; lane fm handles items 2fm, 2fm+1
                if (fm == (item >> 1))
                    atomicAdd(&pooled[g * HD + fb * 16 + quad * 4 + r], t[r]);
            }
        }
    }
    __syncthreads();
    // score head layer 1
    mfma_layer128(aH, aL, m1h, m1l, nb1, lane, acc);
    __syncthreads();
    store_act_leaky(aH, aL, lane, acc);
    __syncthreads();
    // score head layer 2 + dot w3 + sigmoid
    mfma_layer128(aH, aL, m2h, m2l, nb2, lane, acc);
    float v = 0.0f;
    #pragma unroll
    for (int fb = 0; fb < 8; ++fb) {
        const float4 w3v = *(const float4*)&nw3[fb * 16 + quad * 4];
        v += leakyf(acc[fb][0]) * w3v.x + leakyf(acc[fb][1]) * w3v.y
           + leakyf(acc[fb][2]) * w3v.z + leakyf(acc[fb][3]) * w3v.w;
    }
    v += __shfl_xor(v, 16, 64);
    v += __shfl_xor(v, 32, 64);
    if (lane < 16) {
        const int node = tile * 16 + fm;
        const float s = v + nb3[0];
        scores[(node & 63) * NPER + (node >> 6)] = 1.0f / (1.0f + expf(-s));
    }
}

// ---------------- action head: pooled mean -> MLP -> softmax ----------------
__global__ __launch_bounds__(128) void act_kernel(
    const float* __restrict__ pooled,
    const float* __restrict__ w1, const float* __restrict__ b1,
    const float* __restrict__ w2, const float* __restrict__ b2,
    float* __restrict__ out)
{
    __shared__ __align__(16) float p[HD];
    __shared__ float a1[HD];
    __shared__ float z[NACT];
    __shared__ float red2[2];
    const int g = blockIdx.x;
    const int tid = threadIdx.x;
    p[tid] = pooled[g * HD + tid] * (1.0f / NPER);
    __syncthreads();
    float acc = b1[tid];
    for (int k = 0; k < HD; ++k) acc = fmaf(p[k], w1[k * HD + tid], acc);
    a1[tid] = leakyf(acc);
    __syncthreads();
    if (tid < NACT) {
        float a2 = b2[tid];
        for (int k = 0; k < HD; ++k) a2 = fmaf(a1[k], w2[k * NACT + tid], a2);
        z[tid] = leakyf(a2);
    }
    __syncthreads();
    if (tid == 0) {
        float m = z[0];
        for (int i = 1; i < NACT; ++i) m = fmaxf(m, z[i]);
        red2[0] = m;
    }
    __syncthreads();
    if (tid < NACT) z[tid] = expf(z[tid] - red2[0]);
    __syncthreads();
    if (tid == 0) {
        float s = 0.0f;
        for (int i = 0; i < NACT; ++i) s += z[i];
        red2[1] = s;
    }
    __syncthreads();
    if (tid < NACT) out[g * NACT + tid] = z[tid] / red2[1];
}

extern "C" void kernel_launch(void* const* d_in, const int* in_sizes, int n_in,
                              void* d_out, int out_size, void* d_ws, size_t ws_size,
                              hipStream_t stream)
{
    const float* x    = (const float*)d_in[0];
    const int*   ei   = (const int*)d_in[1];     // int32
    const float* ea   = (const float*)d_in[2];
    const float* e1w  = (const float*)d_in[3];
    const float* e1b  = (const float*)d_in[4];
    const float* c1w1 = (const float*)d_in[5];
    const float* c1b1 = (const float*)d_in[6];
    const float* c1w2 = (const float*)d_in[7];
    const float* c1b2 = (const float*)d_in[8];
    const float* e2w  = (const float*)d_in[9];
    const float* e2b  = (const float*)d_in[10];
    const float* c2w1 = (const float*)d_in[11];
    const float* c2b1 = (const float*)d_in[12];
    const float* c2w2 = (const float*)d_in[13];
    const float* c2b2 = (const float*)d_in[14];
    const float* aw1  = (const float*)d_in[15];
    const float* ab1  = (const float*)d_in[16];
    const float* aw2  = (const float*)d_in[17];
    const float* ab2  = (const float*)d_in[18];
    const float* nw1  = (const float*)d_in[19];
    const float* nb1  = (const float*)d_in[20];
    const float* nw2  = (const float*)d_in[21];
    const float* nb2  = (const float*)d_in[22];
    const float* nw3  = (const float*)d_in[23];
    const float* nb3  = (const float*)d_in[24];

    float* out = (float*)d_out;
    char*  ws  = (char*)d_ws;
    const size_t MB = 1024 * 1024;
    // ws: h 0-32 | agg2 32-64 | sea 64-128 | agg1 128-136 | pooled@136 (32K) |
    //     packed weights @136MB+64K (6 x 64K) | cnt 137 | fill 138 | rs 139 | ssrc 140-144
    float* h      = (float*)(ws);
    float* agg2   = (float*)(ws + 32  * MB);
    float* sea    = (float*)(ws + 64  * MB);
    float* agg1   = (float*)(ws + 128 * MB);
    float* pooled = (float*)(ws + 136 * MB);
    u16*   pw     = (u16*)  (ws + 136 * MB + 64 * 1024);
    int*   cnt    = (int*)  (ws + 137 * MB);
    int*   fill   = (int*)  (ws + 138 * MB);
    int*   rs     = (int*)  (ws + 139 * MB);
    int*   ssrc   = (int*)  (ws + 140 * MB);

    // packed regions: per matrix 32768 u16 (hi at +0, lo at +16384)
    u16* p_c1w1 = pw;               // KB=1
    u16* p_c1w2 = pw + 1 * 32768;   // KB=4
    u16* p_c2w1 = pw + 2 * 32768;
    u16* p_c2w2 = pw + 3 * 32768;
    u16* p_nw1  = pw + 4 * 32768;
    u16* p_nw2  = pw + 5 * 32768;

    hipMemsetAsync(cnt,    0, NNODES * sizeof(int), stream);
    hipMemsetAsync(fill,   0, NNODES * sizeof(int), stream);
    hipMemsetAsync(pooled, 0, (size_t)NB * HD * sizeof(float), stream);

    // weight packing (bf16 hi/lo, MFMA fragment order)
    pack_w_kernel<<<16,  256, 0, stream>>>(c1w1, 1, p_c1w1, p_c1w1 + 16384);
    pack_w_kernel<<<64,  256, 0, stream>>>(c1w2, 4, p_c1w2, p_c1w2 + 16384);
    pack_w_kernel<<<64,  256, 0, stream>>>(c2w1, 4, p_c2w1, p_c2w1 + 16384);
    pack_w_kernel<<<64,  256, 0, stream>>>(c2w2, 4, p_c2w2, p_c2w2 + 16384);
    pack_w_kernel<<<64,  256, 0, stream>>>(nw1,  4, p_nw1,  p_nw1  + 16384);
    pack_w_kernel<<<64,  256, 0, stream>>>(nw2,  4, p_nw2,  p_nw2  + 16384);

    // CSR build
    hist_kernel<<<NEDGES / 256, 256, 0, stream>>>(ei, cnt);
    scan_kernel<<<1, 1024, 0, stream>>>(cnt, rs);
    scatter_kernel<<<NEDGES / 256, 256, 0, stream>>>(ei, ea, rs, fill, ssrc, sea);

    e1_agg_kernel<<<NNODES / 4, 256, 0, stream>>>(x, rs, ssrc, sea, e1w, e1b, agg1);
    n1_kernel<<<NNODES / 64, 256, 0, stream>>>(x, agg1,
                                               p_c1w1, p_c1w1 + 16384, c1b1,
                                               p_c1w2, p_c1w2 + 16384, c1b2, h);
    e2_agg_kernel<<<NNODES / 4, 256, 0, stream>>>(h, rs, ssrc, sea, e2w, e2b, agg2);
    n2_kernel<<<NNODES / 64, 256, 0, stream>>>(h, agg2,
                                               p_c2w1, p_c2w1 + 16384, c2b1,
                                               p_c2w2, p_c2w2 + 16384, c2b2,
                                               p_nw1,  p_nw1  + 16384, nb1,
                                               p_nw2,  p_nw2  + 16384, nb2,
                                               nw3, nb3, pooled, out + NB * NACT);
    act_kernel<<<NB, 128, 0, stream>>>(pooled, aw1, ab1, aw2, ab2, out);
}

// Round 7
// 581.811 us; speedup vs baseline: 1.4809x; 1.0162x over previous
//
#include <hip/hip_runtime.h>
#include <math.h>

#define NNODES 65536
#define NEDGES 1048576
#define NF 32
#define EF 16
#define HD 128
#define NACT 10
#define NB 64
#define NPER 1024

typedef unsigned short u16;
typedef float  vf4  __attribute__((ext_vector_type(4)));
typedef __bf16 vbf8 __attribute__((ext_vector_type(8)));
#define BC8(v) __builtin_bit_cast(vbf8, v)

__device__ __forceinline__ float leakyf(float v) { return v > 0.0f ? v : 0.01f * v; }

__device__ __forceinline__ u16 f2bf(float x) {
    unsigned u = __float_as_uint(x);
    return (u16)((u + 0x7FFFu + ((u >> 16) & 1u)) >> 16);
}
__device__ __forceinline__ float bf2f(u16 h) { return __uint_as_float(((unsigned)h) << 16); }

// split f32x4 into bf16-hi and bf16-lo packed pairs (hi + lo ~= full f32 precision)
__device__ __forceinline__ void cvt4(const float4 s, uint2& hi, uint2& lo) {
    const u16 h0 = f2bf(s.x), h1 = f2bf(s.y), h2 = f2bf(s.z), h3 = f2bf(s.w);
    hi = make_uint2((unsigned)h0 | ((unsigned)h1 << 16), (unsigned)h2 | ((unsigned)h3 << 16));
    const u16 l0 = f2bf(s.x - bf2f(h0)), l1 = f2bf(s.y - bf2f(h1));
    const u16 l2 = f2bf(s.z - bf2f(h2)), l3 = f2bf(s.w - bf2f(h3));
    lo = make_uint2((unsigned)l0 | ((unsigned)l1 << 16), (unsigned)l2 | ((unsigned)l3 << 16));
}

// ---------------- CSR build: histogram -> scan -> scatter(idx) -> gather-permute ----------------
__global__ __launch_bounds__(256) void hist_kernel(const int* __restrict__ ei, int* __restrict__ cnt)
{
    const int i = blockIdx.x * 256 + threadIdx.x;
    if (i < NEDGES) atomicAdd(&cnt[ei[NEDGES + i]], 1);
}

__global__ __launch_bounds__(1024) void scan_kernel(const int* __restrict__ cnt, int* __restrict__ rs)
{
    __shared__ int s[1024];
    const int t = threadIdx.x;
    int loc[64];
    int tot = 0;
    const int4* c4 = (const int4*)(cnt + t * 64);
    #pragma unroll
    for (int j = 0; j < 16; ++j) {
        const int4 v = c4[j];
        loc[4*j+0] = v.x; loc[4*j+1] = v.y; loc[4*j+2] = v.z; loc[4*j+3] = v.w;
        tot += v.x + v.y + v.z + v.w;
    }
    s[t] = tot;
    __syncthreads();
    for (int off = 1; off < 1024; off <<= 1) {
        const int v = (t >= off) ? s[t - off] : 0;
        __syncthreads();
        s[t] += v;
        __syncthreads();
    }
    int run = s[t] - tot;
    #pragma unroll
    for (int j = 0; j < 64; ++j) { rs[t * 64 + j] = run; run += loc[j]; }
    if (t == 0) rs[NNODES] = NEDGES;
}

// writes only the permutation (4B random writes -> L2-absorbable), no 64B payload scatter
__global__ __launch_bounds__(256) void scatter_kernel(
    const int* __restrict__ ei, const int* __restrict__ rs, int* __restrict__ fill,
    int* __restrict__ ssrc, int* __restrict__ seidx)
{
    const int i = blockIdx.x * 256 + threadIdx.x;
    if (i < NEDGES) {
        const int d = ei[NEDGES + i];
        const int pos = rs[d] + atomicAdd(&fill[d], 1);
        ssrc[pos]  = ei[i];
        seidx[pos] = i;
    }
}

// gather-based payload permute: random 64B READS (coalesced per edge), sequential writes
__global__ __launch_bounds__(256) void permute_kernel(
    const int* __restrict__ seidx, const float* __restrict__ ea, float* __restrict__ sea)
{
    const int t = blockIdx.x * 256 + threadIdx.x;
    const int e = t >> 2, part = t & 3;        // 4 lanes per edge -> one 64B request
    const int idx = seidx[e];
    ((float4*)sea)[(size_t)e * 4 + part] = ((const float4*)ea)[(size_t)idx * 4 + part];
}

// ---------------- weight packing (all 6 matrices, one launch) ----------------
// A-frag element for (fb, kb, lane, j): W[kb*32 + (lane>>4)*8 + j][fb*16 + (lane&15)]
__global__ __launch_bounds__(256) void pack_all_kernel(
    const float* __restrict__ w0, const float* __restrict__ w1, const float* __restrict__ w2,
    const float* __restrict__ w3, const float* __restrict__ w4, const float* __restrict__ w5,
    u16* __restrict__ pw)
{
    const int bid = blockIdx.x;
    const float* W; int KB, seg, sbase;
    if (bid < 16) { W = w0; KB = 1; seg = 0; sbase = 0; }
    else {
        const int i = (bid - 16) >> 6;
        seg = i + 1; sbase = 16 + i * 64; KB = 4;
        W = (i == 0) ? w1 : (i == 1) ? w2 : (i == 2) ? w3 : (i == 3) ? w4 : w5;
    }
    const int t = (bid - sbase) * 256 + threadIdx.x;
    const int j = t & 7, lane = (t >> 3) & 63, rest = t >> 9;
    const int kb = rest % KB, fb = rest / KB;
    if (fb >= 8) return;
    const int k = kb * 32 + (lane >> 4) * 8 + j;
    const int f = fb * 16 + (lane & 15);
    const float val = W[k * HD + f];
    const u16 h = f2bf(val);
    u16* dst = pw + seg * 32768;
    dst[t] = h;
    dst[16384 + t] = f2bf(val - bf2f(h));
}

// ---------------- edge layer 1 (gather) — R2-proven version ----------------
__global__ __launch_bounds__(256) void e1_agg_kernel(
    const float* __restrict__ x, const int* __restrict__ rs,
    const int* __restrict__ ssrc, const float* __restrict__ sea,
    const float* __restrict__ w, const float* __restrict__ b, float* __restrict__ agg)
{
    const int tid  = threadIdx.x;
    const int lane = tid & 63;
    const int f    = lane & 31;
    const int half = lane >> 5;
    const int node = blockIdx.x * 4 + (tid >> 6);
    float wr[EF];
    #pragma unroll
    for (int k = 0; k < EF; ++k) wr[k] = w[k * NF + f];
    const float bf = b[f];
    const int beg = rs[node], end = rs[node + 1];
    float acc = 0.0f;
    int e = beg + half;
    for (; e + 2 < end; e += 4) {
        const int sA = ssrc[e], sB = ssrc[e + 2];
        const float4* pA = (const float4*)sea + (size_t)e * 4;
        const float4* pB = (const float4*)sea + (size_t)(e + 2) * 4;
        const float4 A0 = pA[0], A1 = pA[1], A2 = pA[2], A3 = pA[3];
        const float4 B0 = pB[0], B1 = pB[1], B2 = pB[2], B3 = pB[3];
        const float xA = x[(size_t)sA * NF + f];
        const float xB = x[(size_t)sB * NF + f];
        float evA[EF] = {A0.x,A0.y,A0.z,A0.w, A1.x,A1.y,A1.z,A1.w,
                         A2.x,A2.y,A2.z,A2.w, A3.x,A3.y,A3.z,A3.w};
        float evB[EF] = {B0.x,B0.y,B0.z,B0.w, B1.x,B1.y,B1.z,B1.w,
                         B2.x,B2.y,B2.z,B2.w, B3.x,B3.y,B3.z,B3.w};
        float mA = bf, mB = bf;
        #pragma unroll
        for (int k = 0; k < EF; ++k) {
            mA = fmaf(evA[k], wr[k], mA);
            mB = fmaf(evB[k], wr[k], mB);
        }
        acc += fmaxf(xA + mA, 0.0f) + fmaxf(xB + mB, 0.0f);
    }
    for (; e < end; e += 2) {
        const int sA = ssrc[e];
        const float4* pA = (const float4*)sea + (size_t)e * 4;
        const float4 A0 = pA[0], A1 = pA[1], A2 = pA[2], A3 = pA[3];
        float evA[EF] = {A0.x,A0.y,A0.z,A0.w, A1.x,A1.y,A1.z,A1.w,
                         A2.x,A2.y,A2.z,A2.w, A3.x,A3.y,A3.z,A3.w};
        float mA = bf;
        #pragma unroll
        for (int k = 0; k < EF; ++k) mA = fmaf(evA[k], wr[k], mA);
        acc += fmaxf(x[(size_t)sA * NF + f] + mA, 0.0f);
    }
    acc += __shfl_xor(acc, 32, 64);
    if (half == 0) agg[(size_t)node * NF + f] = acc;
}

// ---------------- edge layer 2 (gather) — scalar-uniform version ----------------
__global__ __launch_bounds__(256) void e2_agg_kernel(
    const float* __restrict__ h, const int* __restrict__ rs,
    const int* __restrict__ ssrc, const float* __restrict__ sea,
    const float* __restrict__ w, const float* __restrict__ b, float* __restrict__ agg)
{
    const int tid  = threadIdx.x;
    const int lane = tid & 63;
    const int f    = lane * 2;
    const int node = blockIdx.x * 4 + (tid >> 6);
    float wr0[EF], wr1[EF];
    #pragma unroll
    for (int k = 0; k < EF; ++k) { wr0[k] = w[k * HD + f]; wr1[k] = w[k * HD + f + 1]; }
    const float b0 = b[f], b1 = b[f + 1];
    const int beg = __builtin_amdgcn_readfirstlane(rs[node]);
    const int end = __builtin_amdgcn_readfirstlane(rs[node + 1]);
    float acc0 = 0.0f, acc1 = 0.0f;
    int e = beg;
    for (; e + 2 <= end; e += 2) {
        const int sA = ssrc[e];
        const int sB = ssrc[e + 1];
        const float2 hA = *(const float2*)&h[(size_t)sA * HD + f];
        const float2 hB = *(const float2*)&h[(size_t)sB * HD + f];
        const float* aA = &sea[(size_t)e * EF];
        const float* aB = aA + EF;
        float mA0 = b0, mA1 = b1, mB0 = b0, mB1 = b1;
        #pragma unroll
        for (int k = 0; k < EF; ++k) {
            const float vA = aA[k];
            const float vB = aB[k];
            mA0 = fmaf(vA, wr0[k], mA0);
            mA1 = fmaf(vA, wr1[k], mA1);
            mB0 = fmaf(vB, wr0[k], mB0);
            mB1 = fmaf(vB, wr1[k], mB1);
        }
        acc0 += fmaxf(hA.x + mA0, 0.0f) + fmaxf(hB.x + mB0, 0.0f);
        acc1 += fmaxf(hA.y + mA1, 0.0f) + fmaxf(hB.y + mB1, 0.0f);
    }
    if (e < end) {
        const int sA = ssrc[e];
        const float2 hA = *(const float2*)&h[(size_t)sA * HD + f];
        const float* aA = &sea[(size_t)e * EF];
        float mA0 = b0, mA1 = b1;
        #pragma unroll
        for (int k = 0; k < EF; ++k) {
            const float vA = aA[k];
            mA0 = fmaf(vA, wr0[k], mA0);
            mA1 = fmaf(vA, wr1[k], mA1);
        }
        acc0 += fmaxf(hA.x + mA0, 0.0f);
        acc1 += fmaxf(hA.y + mA1, 0.0f);
    }
    *(float2*)&agg[(size_t)node * HD + f] = make_float2(acc0, acc1);
}

// ---------------- MFMA node-GEMM building blocks ----------------
#define ROW128 272   // 128 bf16 = 256 B + 16 pad
#define ROW32  80    // 32 bf16 = 64 B + 16 pad

__device__ __forceinline__ void mfma_layer128(
    const unsigned char* __restrict__ aH, const unsigned char* __restrict__ aL,
    const u16* __restrict__ wH, const u16* __restrict__ wL,
    const float* __restrict__ bias, int lane, vf4* __restrict__ acc)
{
    const int quad = lane >> 4, fm = lane & 15;
    int4 Bh[4], Bl[4];
    #pragma unroll
    for (int kb = 0; kb < 4; ++kb) {
        Bh[kb] = *(const int4*)(aH + fm * ROW128 + kb * 64 + quad * 16);
        Bl[kb] = *(const int4*)(aL + fm * ROW128 + kb * 64 + quad * 16);
    }
    #pragma unroll
    for (int fb = 0; fb < 8; ++fb) {
        const float4 bv = *(const float4*)&bias[fb * 16 + quad * 4];
        vf4 a = {bv.x, bv.y, bv.z, bv.w};
        #pragma unroll
        for (int kb = 0; kb < 4; ++kb) {
            const int4 wh = *(const int4*)(wH + ((fb * 4 + kb) * 64 + lane) * 8);
            const int4 wl = *(const int4*)(wL + ((fb * 4 + kb) * 64 + lane) * 8);
            a = __builtin_amdgcn_mfma_f32_16x16x32_bf16(BC8(wh), BC8(Bl[kb]), a, 0, 0, 0);
            a = __builtin_amdgcn_mfma_f32_16x16x32_bf16(BC8(wl), BC8(Bh[kb]), a, 0, 0, 0);
            a = __builtin_amdgcn_mfma_f32_16x16x32_bf16(BC8(wh), BC8(Bh[kb]), a, 0, 0, 0);
        }
        acc[fb] = a;
    }
}

__device__ __forceinline__ void mfma_layer32(
    const unsigned char* __restrict__ aH, const unsigned char* __restrict__ aL,
    const u16* __restrict__ wH, const u16* __restrict__ wL,
    const float* __restrict__ bias, int lane, vf4* __restrict__ acc)
{
    const int quad = lane >> 4, fm = lane & 15;
    const int4 Bh = *(const int4*)(aH + fm * ROW32 + quad * 16);
    const int4 Bl = *(const int4*)(aL + fm * ROW32 + quad * 16);
    #pragma unroll
    for (int fb = 0; fb < 8; ++fb) {
        const float4 bv = *(const float4*)&bias[fb * 16 + quad * 4];
        vf4 a = {bv.x, bv.y, bv.z, bv.w};
        const int4 wh = *(const int4*)(wH + (fb * 64 + lane) * 8);
        const int4 wl = *(const int4*)(wL + (fb * 64 + lane) * 8);
        a = __builtin_amdgcn_mfma_f32_16x16x32_bf16(BC8(wh), BC8(Bl), a, 0, 0, 0);
        a = __builtin_amdgcn_mfma_f32_16x16x32_bf16(BC8(wl), BC8(Bh), a, 0, 0, 0);
        a = __builtin_amdgcn_mfma_f32_16x16x32_bf16(BC8(wh), BC8(Bh), a, 0, 0, 0);
        acc[fb] = a;
    }
}

__device__ __forceinline__ void store_act_leaky(
    unsigned char* __restrict__ aH, unsigned char* __restrict__ aL, int lane, vf4* __restrict__ acc)
{
    const int quad = lane >> 4, fm = lane & 15;
    #pragma unroll
    for (int fb = 0; fb < 8; ++fb) {
        const float4 s = {leakyf(acc[fb][0]), leakyf(acc[fb][1]), leakyf(acc[fb][2]), leakyf(acc[fb][3])};
        acc[fb][0] = s.x; acc[fb][1] = s.y; acc[fb][2] = s.z; acc[fb][3] = s.w;
        uint2 phi, plo;
        cvt4(s, phi, plo);
        *(uint2*)(aH + fm * ROW128 + fb * 32 + quad * 8) = phi;
        *(uint2*)(aL + fm * ROW128 + fb * 32 + quad * 8) = plo;
    }
}

// ---------------- node MLP layer 1 (MFMA) ----------------
__global__ __launch_bounds__(256) void n1_kernel(
    const float* __restrict__ x, const float* __restrict__ agg,
    const u16* __restrict__ w1h, const u16* __restrict__ w1l, const float* __restrict__ b1,
    const u16* __restrict__ w2h, const u16* __restrict__ w2l, const float* __restrict__ b2,
    float* __restrict__ hout)
{
    __shared__ __align__(16) unsigned char smem[4][2560 + 2 * 16 * ROW128];
    const int tid = threadIdx.x, lane = tid & 63, wid = tid >> 6;
    const int quad = lane >> 4, fm = lane & 15;
    const int tile = blockIdx.x * 4 + wid;
    unsigned char* inH = smem[wid];
    unsigned char* inL = inH + 16 * ROW32;
    unsigned char* aH  = inH + 2560;
    unsigned char* aL  = aH + 16 * ROW128;
    const size_t base = (size_t)tile * 16 * NF;
    #pragma unroll
    for (int i = 0; i < 2; ++i) {
        const int flat = i * 64 + lane;
        const int node = flat >> 3, kq = flat & 7;
        const float4 xv = *(const float4*)&x[base + node * NF + kq * 4];
        const float4 av = *(const float4*)&agg[base + node * NF + kq * 4];
        const float4 s = {xv.x + av.x, xv.y + av.y, xv.z + av.z, xv.w + av.w};
        uint2 phi, plo;
        cvt4(s, phi, plo);
        *(uint2*)(inH + node * ROW32 + kq * 8) = phi;
        *(uint2*)(inL + node * ROW32 + kq * 8) = plo;
    }
    __syncthreads();
    vf4 acc[8];
    mfma_layer32(inH, inL, w1h, w1l, b1, lane, acc);
    __syncthreads();
    store_act_leaky(aH, aL, lane, acc);
    __syncthreads();
    mfma_layer128(aH, aL, w2h, w2l, b2, lane, acc);
    const size_t ob = (size_t)tile * 16 * HD;
    #pragma unroll
    for (int fb = 0; fb < 8; ++fb) {
        const float4 o = {fmaxf(acc[fb][0], 0.0f), fmaxf(acc[fb][1], 0.0f),
                          fmaxf(acc[fb][2], 0.0f), fmaxf(acc[fb][3], 0.0f)};
        *(float4*)&hout[ob + fm * HD + fb * 16 + quad * 4] = o;
    }
}

// ---- node layer 2 + pooling + node-score head (MFMA, h2 never leaves the CU) ----
__global__ __launch_bounds__(256) void n2_kernel(
    const float* __restrict__ h, const float* __restrict__ agg,
    const u16* __restrict__ w1h, const u16* __restrict__ w1l, const float* __restrict__ b1,
    const u16* __restrict__ w2h, const u16* __restrict__ w2l, const float* __restrict__ b2,
    const u16* __restrict__ m1h, const u16* __restrict__ m1l, const float* __restrict__ nb1,
    const u16* __restrict__ m2h, const u16* __restrict__ m2l, const float* __restrict__ nb2,
    const float* __restrict__ nw3, const float* __restrict__ nb3,
    float* __restrict__ pooled, float* __restrict__ scores)
{
    __shared__ __align__(16) unsigned char smem[4][2 * 16 * ROW128];
    const int tid = threadIdx.x, lane = tid & 63, wid = tid >> 6;
    const int quad = lane >> 4, fm = lane & 15;
    const int tile = blockIdx.x * 4 + wid;
    unsigned char* aH = smem[wid];
    unsigned char* aL = aH + 16 * ROW128;
    const size_t base = (size_t)tile * 16 * HD;
    #pragma unroll
    for (int i = 0; i < 8; ++i) {
        const int flat = i * 64 + lane;
        const int node = flat >> 5, kq = flat & 31;
        const float4 hv = *(const float4*)&h[base + node * HD + kq * 4];
        const float4 av = *(const float4*)&agg[base + node * HD + kq * 4];
        const float4 s = {hv.x + av.x, hv.y + av.y, hv.z + av.z, hv.w + av.w};
        uint2 phi, plo;
        cvt4(s, phi, plo);
        *(uint2*)(aH + node * ROW128 + kq * 8) = phi;
        *(uint2*)(aL + node * ROW128 + kq * 8) = plo;
    }
    __syncthreads();
    vf4 acc[8];
    mfma_layer128(aH, aL, w1h, w1l, b1, lane, acc);
    __syncthreads();
    store_act_leaky(aH, aL, lane, acc);
    __syncthreads();
    mfma_layer128(aH, aL, w2h, w2l, b2, lane, acc);
    __syncthreads();
    store_act_leaky(aH, aL, lane, acc);          // acc now holds h2 (leaky'd)
    {
        const int g = tile >> 6;
        #pragma unroll
        for (int fb = 0; fb < 8; ++fb) {
            vf4 t = acc[fb];
            #pragma unroll
            for (int off = 1; off < 16; off <<= 1) {
                t[0] += __shfl_xor(t[0], off, 64);
                t[1] += __shfl_xor(t[1], off, 64);
                t[2] += __shfl_xor(t[2], off, 64);
                t[3] += __shfl_xor(t[3], off, 64);
            }
            #pragma unroll
            for (int r = 0; r < 4; ++r) {
                const int item = fb * 4 + r;
                if (fm == (item >> 1))
                    atomicAdd(&pooled[g * HD + fb * 16 + quad * 4 + r], t[r]);
            }
        }
    }
    __syncthreads();
    mfma_layer128(aH, aL, m1h, m1l, nb1, lane, acc);
    __syncthreads();
    store_act_leaky(aH, aL, lane, acc);
    __syncthreads();
    mfma_layer128(aH, aL, m2h, m2l, nb2, lane, acc);
    float v = 0.0f;
    #pragma unroll
    for (int fb = 0; fb < 8; ++fb) {
        const float4 w3v = *(const float4*)&nw3[fb * 16 + quad * 4];
        v += leakyf(acc[fb][0]) * w3v.x + leakyf(acc[fb][1]) * w3v.y
           + leakyf(acc[fb][2]) * w3v.z + leakyf(acc[fb][3]) * w3v.w;
    }
    v += __shfl_xor(v, 16, 64);
    v += __shfl_xor(v, 32, 64);
    if (lane < 16) {
        const int node = tile * 16 + fm;
        const float s = v + nb3[0];
        scores[(node & 63) * NPER + (node >> 6)] = 1.0f / (1.0f + expf(-s));
    }
}

// ---------------- action head: pooled mean -> MLP -> softmax ----------------
__global__ __launch_bounds__(128) void act_kernel(
    const float* __restrict__ pooled,
    const float* __restrict__ w1, const float* __restrict__ b1,
    const float* __restrict__ w2, const float* __restrict__ b2,
    float* __restrict__ out)
{
    __shared__ __align__(16) float p[HD];
    __shared__ float a1[HD];
    __shared__ float z[NACT];
    __shared__ float red2[2];
    const int g = blockIdx.x;
    const int tid = threadIdx.x;
    p[tid] = pooled[g * HD + tid] * (1.0f / NPER);
    __syncthreads();
    float acc = b1[tid];
    for (int k = 0; k < HD; ++k) acc = fmaf(p[k], w1[k * HD + tid], acc);
    a1[tid] = leakyf(acc);
    __syncthreads();
    if (tid < NACT) {
        float a2 = b2[tid];
        for (int k = 0; k < HD; ++k) a2 = fmaf(a1[k], w2[k * NACT + tid], a2);
        z[tid] = leakyf(a2);
    }
    __syncthreads();
    if (tid == 0) {
        float m = z[0];
        for (int i = 1; i < NACT; ++i) m = fmaxf(m, z[i]);
        red2[0] = m;
    }
    __syncthreads();
    if (tid < NACT) z[tid] = expf(z[tid] - red2[0]);
    __syncthreads();
    if (tid == 0) {
        float s = 0.0f;
        for (int i = 0; i < NACT; ++i) s += z[i];
        red2[1] = s;
    }
    __syncthreads();
    if (tid < NACT) out[g * NACT + tid] = z[tid] / red2[1];
}

extern "C" void kernel_launch(void* const* d_in, const int* in_sizes, int n_in,
                              void* d_out, int out_size, void* d_ws, size_t ws_size,
                              hipStream_t stream)
{
    const float* x    = (const float*)d_in[0];
    const int*   ei   = (const int*)d_in[1];     // int32
    const float* ea   = (const float*)d_in[2];
    const float* e1w  = (const float*)d_in[3];
    const float* e1b  = (const float*)d_in[4];
    const float* c1w1 = (const float*)d_in[5];
    const float* c1b1 = (const float*)d_in[6];
    const float* c1w2 = (const float*)d_in[7];
    const float* c1b2 = (const float*)d_in[8];
    const float* e2w  = (const float*)d_in[9];
    const float* e2b  = (const float*)d_in[10];
    const float* c2w1 = (const float*)d_in[11];
    const float* c2b1 = (const float*)d_in[12];
    const float* c2w2 = (const float*)d_in[13];
    const float* c2b2 = (const float*)d_in[14];
    const float* aw1  = (const float*)d_in[15];
    const float* ab1  = (const float*)d_in[16];
    const float* aw2  = (const float*)d_in[17];
    const float* ab2  = (const float*)d_in[18];
    const float* nw1  = (const float*)d_in[19];
    const float* nb1  = (const float*)d_in[20];
    const float* nw2  = (const float*)d_in[21];
    const float* nb2  = (const float*)d_in[22];
    const float* nw3  = (const float*)d_in[23];
    const float* nb3  = (const float*)d_in[24];

    float* out = (float*)d_out;
    char*  ws  = (char*)d_ws;
    const size_t MB = 1024 * 1024;
    // ws (144 MB): h 0-32 | agg2 32-64 (seidx aliases its first 4 MB until e2 runs) |
    //   sea 64-128 | agg1 128-136 | pooled@136 | packed w @136MB+64K | cnt/fill 137 | rs 139 | ssrc 140
    float* h      = (float*)(ws);
    float* agg2   = (float*)(ws + 32  * MB);
    int*   seidx  = (int*)  (ws + 32  * MB);     // dead before e2_agg writes agg2
    float* sea    = (float*)(ws + 64  * MB);
    float* agg1   = (float*)(ws + 128 * MB);
    float* pooled = (float*)(ws + 136 * MB);
    u16*   pw     = (u16*)  (ws + 136 * MB + 64 * 1024);
    int*   cnt    = (int*)  (ws + 137 * MB);
    int*   fill   = (int*)  (ws + 137 * MB + 256 * 1024);
    int*   rs     = (int*)  (ws + 139 * MB);
    int*   ssrc   = (int*)  (ws + 140 * MB);

    u16* p_c1w1 = pw;
    u16* p_c1w2 = pw + 1 * 32768;
    u16* p_c2w1 = pw + 2 * 32768;
    u16* p_c2w2 = pw + 3 * 32768;
    u16* p_nw1  = pw + 4 * 32768;
    u16* p_nw2  = pw + 5 * 32768;

    hipMemsetAsync(cnt,    0, 2 * NNODES * sizeof(int), stream);   // cnt + fill (adjacent)
    hipMemsetAsync(pooled, 0, (size_t)NB * HD * sizeof(float), stream);

    pack_all_kernel<<<336, 256, 0, stream>>>(c1w1, c1w2, c2w1, c2w2, nw1, nw2, pw);

    // CSR build: permutation only, then gather-based payload permute
    hist_kernel<<<NEDGES / 256, 256, 0, stream>>>(ei, cnt);
    scan_kernel<<<1, 1024, 0, stream>>>(cnt, rs);
    scatter_kernel<<<NEDGES / 256, 256, 0, stream>>>(ei, rs, fill, ssrc, seidx);
    permute_kernel<<<NEDGES / 64, 256, 0, stream>>>(seidx, ea, sea);

    e1_agg_kernel<<<NNODES / 4, 256, 0, stream>>>(x, rs, ssrc, sea, e1w, e1b, agg1);
    n1_kernel<<<NNODES / 64, 256, 0, stream>>>(x, agg1,
                                               p_c1w1, p_c1w1 + 16384, c1b1,
                                               p_c1w2, p_c1w2 + 16384, c1b2, h);
    e2_agg_kernel<<<NNODES / 4, 256, 0, stream>>>(h, rs, ssrc, sea, e2w, e2b, agg2);
    n2_kernel<<<NNODES / 64, 256, 0, stream>>>(h, agg2,
                                               p_c2w1, p_c2w1 + 16384, c2b1,
                                               p_c2w2, p_c2w2 + 16384, c2b2,
                                               p_nw1,  p_nw1  + 16384, nb1,
                                               p_nw2,  p_nw2  + 16384, nb2,
                                               nw3, nb3, pooled, out + NB * NACT);
    act_kernel<<<NB, 128, 0, stream>>>(pooled, aw1, ab1, aw2, ab2, out);
}

// Round 8
// 579.821 us; speedup vs baseline: 1.4860x; 1.0034x over previous
//
#include <hip/hip_runtime.h>
#include <math.h>

#define NNODES 65536
#define NEDGES 1048576
#define NF 32
#define EF 16
#define HD 128
#define NACT 10
#define NB 64
#define NPER 1024

typedef unsigned short u16;
typedef float  vf2  __attribute__((ext_vector_type(2)));
typedef float  vf4  __attribute__((ext_vector_type(4)));
typedef __bf16 vbf8 __attribute__((ext_vector_type(8)));
#define BC8(v) __builtin_bit_cast(vbf8, v)

__device__ __forceinline__ float leakyf(float v) { return v > 0.0f ? v : 0.01f * v; }
__device__ __forceinline__ vf2 fma2(vf2 a, vf2 b, vf2 c) { return __builtin_elementwise_fma(a, b, c); }
__device__ __forceinline__ vf2 max2(vf2 a, vf2 b) { return __builtin_elementwise_max(a, b); }
__device__ __forceinline__ vf2 splat2(float s) { vf2 r = {s, s}; return r; }

__device__ __forceinline__ u16 f2bf(float x) {
    unsigned u = __float_as_uint(x);
    return (u16)((u + 0x7FFFu + ((u >> 16) & 1u)) >> 16);
}
__device__ __forceinline__ float bf2f(u16 h) { return __uint_as_float(((unsigned)h) << 16); }

// split f32x4 into bf16-hi and bf16-lo packed pairs (hi + lo ~= full f32 precision)
__device__ __forceinline__ void cvt4(const float4 s, uint2& hi, uint2& lo) {
    const u16 h0 = f2bf(s.x), h1 = f2bf(s.y), h2 = f2bf(s.z), h3 = f2bf(s.w);
    hi = make_uint2((unsigned)h0 | ((unsigned)h1 << 16), (unsigned)h2 | ((unsigned)h3 << 16));
    const u16 l0 = f2bf(s.x - bf2f(h0)), l1 = f2bf(s.y - bf2f(h1));
    const u16 l2 = f2bf(s.z - bf2f(h2)), l3 = f2bf(s.w - bf2f(h3));
    lo = make_uint2((unsigned)l0 | ((unsigned)l1 << 16), (unsigned)l2 | ((unsigned)l3 << 16));
}
// hi-only variant (internal activations)
__device__ __forceinline__ uint2 cvt4hi(const float4 s) {
    const u16 h0 = f2bf(s.x), h1 = f2bf(s.y), h2 = f2bf(s.z), h3 = f2bf(s.w);
    return make_uint2((unsigned)h0 | ((unsigned)h1 << 16), (unsigned)h2 | ((unsigned)h3 << 16));
}

// ---------------- CSR build: histogram -> scan -> scatter(idx) -> gather-permute ----------------
__global__ __launch_bounds__(256) void hist_kernel(const int* __restrict__ ei, int* __restrict__ cnt)
{
    const int i = blockIdx.x * 256 + threadIdx.x;
    if (i < NEDGES) atomicAdd(&cnt[ei[NEDGES + i]], 1);
}

__global__ __launch_bounds__(1024) void scan_kernel(const int* __restrict__ cnt, int* __restrict__ rs)
{
    __shared__ int s[1024];
    const int t = threadIdx.x;
    int loc[64];
    int tot = 0;
    const int4* c4 = (const int4*)(cnt + t * 64);
    #pragma unroll
    for (int j = 0; j < 16; ++j) {
        const int4 v = c4[j];
        loc[4*j+0] = v.x; loc[4*j+1] = v.y; loc[4*j+2] = v.z; loc[4*j+3] = v.w;
        tot += v.x + v.y + v.z + v.w;
    }
    s[t] = tot;
    __syncthreads();
    for (int off = 1; off < 1024; off <<= 1) {
        const int v = (t >= off) ? s[t - off] : 0;
        __syncthreads();
        s[t] += v;
        __syncthreads();
    }
    int run = s[t] - tot;
    #pragma unroll
    for (int j = 0; j < 64; ++j) { rs[t * 64 + j] = run; run += loc[j]; }
    if (t == 0) rs[NNODES] = NEDGES;
}

__global__ __launch_bounds__(256) void scatter_kernel(
    const int* __restrict__ ei, const int* __restrict__ rs, int* __restrict__ fill,
    int* __restrict__ ssrc, int* __restrict__ seidx)
{
    const int i = blockIdx.x * 256 + threadIdx.x;
    if (i < NEDGES) {
        const int d = ei[NEDGES + i];
        const int pos = rs[d] + atomicAdd(&fill[d], 1);
        ssrc[pos]  = ei[i];
        seidx[pos] = i;
    }
}

__global__ __launch_bounds__(256) void permute_kernel(
    const int* __restrict__ seidx, const float* __restrict__ ea, float* __restrict__ sea)
{
    const int t = blockIdx.x * 256 + threadIdx.x;
    const int e = t >> 2, part = t & 3;
    const int idx = seidx[e];
    ((float4*)sea)[(size_t)e * 4 + part] = ((const float4*)ea)[(size_t)idx * 4 + part];
}

// ---------------- weight packing (all 6 matrices, one launch) ----------------
__global__ __launch_bounds__(256) void pack_all_kernel(
    const float* __restrict__ w0, const float* __restrict__ w1, const float* __restrict__ w2,
    const float* __restrict__ w3, const float* __restrict__ w4, const float* __restrict__ w5,
    u16* __restrict__ pw)
{
    const int bid = blockIdx.x;
    const float* W; int KB, seg, sbase;
    if (bid < 16) { W = w0; KB = 1; seg = 0; sbase = 0; }
    else {
        const int i = (bid - 16) >> 6;
        seg = i + 1; sbase = 16 + i * 64; KB = 4;
        W = (i == 0) ? w1 : (i == 1) ? w2 : (i == 2) ? w3 : (i == 3) ? w4 : w5;
    }
    const int t = (bid - sbase) * 256 + threadIdx.x;
    const int j = t & 7, lane = (t >> 3) & 63, rest = t >> 9;
    const int kb = rest % KB, fb = rest / KB;
    if (fb >= 8) return;
    const int k = kb * 32 + (lane >> 4) * 8 + j;
    const int f = fb * 16 + (lane & 15);
    const float val = W[k * HD + f];
    const u16 h = f2bf(val);
    u16* dst = pw + seg * 32768;
    dst[t] = h;
    dst[16384 + t] = f2bf(val - bf2f(h));
}

// ---------------- edge layer 1 (gather): quarter-chains, feature pairs, pk_fma ----------------
__global__ __launch_bounds__(256) void e1_agg_kernel(
    const float* __restrict__ x, const int* __restrict__ rs,
    const int* __restrict__ ssrc, const float* __restrict__ sea,
    const float* __restrict__ w, const float* __restrict__ b, float* __restrict__ agg)
{
    const int tid  = threadIdx.x;
    const int lane = tid & 63;
    const int p    = lane & 15;          // feature pair: f = 2p, 2p+1
    const int q    = lane >> 4;          // edge chain 0..3
    const int node = blockIdx.x * 4 + (tid >> 6);
    vf2 wr[EF];
    #pragma unroll
    for (int k = 0; k < EF; ++k) wr[k] = *(const vf2*)&w[k * NF + p * 2];
    const vf2 bias = *(const vf2*)&b[p * 2];
    const int beg = rs[node], end = rs[node + 1];
    vf2 acc = {0.0f, 0.0f};
    for (int e = beg + q; e < end; e += 4) {
        const int sA = ssrc[e];
        const float4* pA = (const float4*)sea + (size_t)e * 4;
        const float4 A0 = pA[0], A1 = pA[1], A2 = pA[2], A3 = pA[3];
        const vf2 xv = *(const vf2*)((const char*)x + (((unsigned)sA << 7) + (unsigned)p * 8));
        vf2 m = bias;
        m = fma2(splat2(A0.x), wr[0],  m); m = fma2(splat2(A0.y), wr[1],  m);
        m = fma2(splat2(A0.z), wr[2],  m); m = fma2(splat2(A0.w), wr[3],  m);
        m = fma2(splat2(A1.x), wr[4],  m); m = fma2(splat2(A1.y), wr[5],  m);
        m = fma2(splat2(A1.z), wr[6],  m); m = fma2(splat2(A1.w), wr[7],  m);
        m = fma2(splat2(A2.x), wr[8],  m); m = fma2(splat2(A2.y), wr[9],  m);
        m = fma2(splat2(A2.z), wr[10], m); m = fma2(splat2(A2.w), wr[11], m);
        m = fma2(splat2(A3.x), wr[12], m); m = fma2(splat2(A3.y), wr[13], m);
        m = fma2(splat2(A3.z), wr[14], m); m = fma2(splat2(A3.w), wr[15], m);
        acc += max2(xv + m, splat2(0.0f));
    }
    // reduce across the 4 chains (lanes p, p+16, p+32, p+48)
    acc[0] += __shfl_xor(acc[0], 16, 64); acc[1] += __shfl_xor(acc[1], 16, 64);
    acc[0] += __shfl_xor(acc[0], 32, 64); acc[1] += __shfl_xor(acc[1], 32, 64);
    if (lane < 16) *(vf2*)&agg[(size_t)node * NF + p * 2] = acc;
}

// ---------------- edge layer 2 (gather): scalar-uniform sea/ssrc + pk_fma ----------------
__global__ __launch_bounds__(256) void e2_agg_kernel(
    const float* __restrict__ h, const int* __restrict__ rs,
    const int* __restrict__ ssrc, const float* __restrict__ sea,
    const float* __restrict__ w, const float* __restrict__ b, float* __restrict__ agg)
{
    const int tid  = threadIdx.x;
    const int lane = tid & 63;
    const unsigned foff = (unsigned)lane * 8;    // byte offset of feature pair
    const int node = blockIdx.x * 4 + (tid >> 6);
    vf2 wr[EF];
    #pragma unroll
    for (int k = 0; k < EF; ++k) wr[k] = *(const vf2*)&w[k * HD + lane * 2];
    const vf2 bias = *(const vf2*)&b[lane * 2];
    const int beg = __builtin_amdgcn_readfirstlane(rs[node]);
    const int end = __builtin_amdgcn_readfirstlane(rs[node + 1]);
    vf2 acc = {0.0f, 0.0f};
    int e = beg;
    for (; e + 2 <= end; e += 2) {
        const int sA = ssrc[e];                  // uniform -> s_load
        const int sB = ssrc[e + 1];
        const vf2 hA = *(const vf2*)((const char*)h + (((unsigned)sA << 9) + foff));
        const vf2 hB = *(const vf2*)((const char*)h + (((unsigned)sB << 9) + foff));
        const float* aA = &sea[(size_t)e * EF];  // uniform -> s_load_dwordx16
        const float* aB = aA + EF;
        vf2 mA = bias, mB = bias;
        #pragma unroll
        for (int k = 0; k < EF; ++k) {
            mA = fma2(splat2(aA[k]), wr[k], mA);
            mB = fma2(splat2(aB[k]), wr[k], mB);
        }
        acc += max2(hA + mA, splat2(0.0f));
        acc += max2(hB + mB, splat2(0.0f));
    }
    if (e < end) {
        const int sA = ssrc[e];
        const vf2 hA = *(const vf2*)((const char*)h + (((unsigned)sA << 9) + foff));
        const float* aA = &sea[(size_t)e * EF];
        vf2 mA = bias;
        #pragma unroll
        for (int k = 0; k < EF; ++k) mA = fma2(splat2(aA[k]), wr[k], mA);
        acc += max2(hA + mA, splat2(0.0f));
    }
    *(vf2*)&agg[(size_t)node * HD + lane * 2] = acc;
}

// ---------------- MFMA node-GEMM building blocks ----------------
#define ROW128 272   // 128 bf16 = 256 B + 16 pad
#define ROW32  80    // 32 bf16 = 64 B + 16 pad

// layer consuming STAGED input (hi+lo B): 3 MFMAs per (fb,kb)
__device__ __forceinline__ void mfma_layer128_in(
    const unsigned char* __restrict__ aH, const unsigned char* __restrict__ aL,
    const u16* __restrict__ wH, const u16* __restrict__ wL,
    const float* __restrict__ bias, int lane, vf4* __restrict__ acc)
{
    const int quad = lane >> 4, fm = lane & 15;
    int4 Bh[4], Bl[4];
    #pragma unroll
    for (int kb = 0; kb < 4; ++kb) {
        Bh[kb] = *(const int4*)(aH + fm * ROW128 + kb * 64 + quad * 16);
        Bl[kb] = *(const int4*)(aL + fm * ROW128 + kb * 64 + quad * 16);
    }
    #pragma unroll
    for (int fb = 0; fb < 8; ++fb) {
        const float4 bv = *(const float4*)&bias[fb * 16 + quad * 4];
        vf4 a = {bv.x, bv.y, bv.z, bv.w};
        #pragma unroll
        for (int kb = 0; kb < 4; ++kb) {
            const int4 wh = *(const int4*)(wH + ((fb * 4 + kb) * 64 + lane) * 8);
            const int4 wl = *(const int4*)(wL + ((fb * 4 + kb) * 64 + lane) * 8);
            a = __builtin_amdgcn_mfma_f32_16x16x32_bf16(BC8(wh), BC8(Bl[kb]), a, 0, 0, 0);
            a = __builtin_amdgcn_mfma_f32_16x16x32_bf16(BC8(wl), BC8(Bh[kb]), a, 0, 0, 0);
            a = __builtin_amdgcn_mfma_f32_16x16x32_bf16(BC8(wh), BC8(Bh[kb]), a, 0, 0, 0);
        }
        acc[fb] = a;
    }
}

// layer consuming internal ACTIVATIONS (hi-only B): 2 MFMAs per (fb,kb)
__device__ __forceinline__ void mfma_layer128_act(
    const unsigned char* __restrict__ aH,
    const u16* __restrict__ wH, const u16* __restrict__ wL,
    const float* __restrict__ bias, int lane, vf4* __restrict__ acc)
{
    const int quad = lane >> 4, fm = lane & 15;
    int4 Bh[4];
    #pragma unroll
    for (int kb = 0; kb < 4; ++kb)
        Bh[kb] = *(const int4*)(aH + fm * ROW128 + kb * 64 + quad * 16);
    #pragma unroll
    for (int fb = 0; fb < 8; ++fb) {
        const float4 bv = *(const float4*)&bias[fb * 16 + quad * 4];
        vf4 a = {bv.x, bv.y, bv.z, bv.w};
        #pragma unroll
        for (int kb = 0; kb < 4; ++kb) {
            const int4 wh = *(const int4*)(wH + ((fb * 4 + kb) * 64 + lane) * 8);
            const int4 wl = *(const int4*)(wL + ((fb * 4 + kb) * 64 + lane) * 8);
            a = __builtin_amdgcn_mfma_f32_16x16x32_bf16(BC8(wl), BC8(Bh[kb]), a, 0, 0, 0);
            a = __builtin_amdgcn_mfma_f32_16x16x32_bf16(BC8(wh), BC8(Bh[kb]), a, 0, 0, 0);
        }
        acc[fb] = a;
    }
}

__device__ __forceinline__ void mfma_layer32_in(
    const unsigned char* __restrict__ aH, const unsigned char* __restrict__ aL,
    const u16* __restrict__ wH, const u16* __restrict__ wL,
    const float* __restrict__ bias, int lane, vf4* __restrict__ acc)
{
    const int quad = lane >> 4, fm = lane & 15;
    const int4 Bh = *(const int4*)(aH + fm * ROW32 + quad * 16);
    const int4 Bl = *(const int4*)(aL + fm * ROW32 + quad * 16);
    #pragma unroll
    for (int fb = 0; fb < 8; ++fb) {
        const float4 bv = *(const float4*)&bias[fb * 16 + quad * 4];
        vf4 a = {bv.x, bv.y, bv.z, bv.w};
        const int4 wh = *(const int4*)(wH + (fb * 64 + lane) * 8);
        const int4 wl = *(const int4*)(wL + (fb * 64 + lane) * 8);
        a = __builtin_amdgcn_mfma_f32_16x16x32_bf16(BC8(wh), BC8(Bl), a, 0, 0, 0);
        a = __builtin_amdgcn_mfma_f32_16x16x32_bf16(BC8(wl), BC8(Bh), a, 0, 0, 0);
        a = __builtin_amdgcn_mfma_f32_16x16x32_bf16(BC8(wh), BC8(Bh), a, 0, 0, 0);
        acc[fb] = a;
    }
}

// apply leaky, write hi-only activations to LDS (acc updated to post-activation values)
__device__ __forceinline__ void store_act_hi(
    unsigned char* __restrict__ aH, int lane, vf4* __restrict__ acc)
{
    const int quad = lane >> 4, fm = lane & 15;
    #pragma unroll
    for (int fb = 0; fb < 8; ++fb) {
        const float4 s = {leakyf(acc[fb][0]), leakyf(acc[fb][1]), leakyf(acc[fb][2]), leakyf(acc[fb][3])};
        acc[fb][0] = s.x; acc[fb][1] = s.y; acc[fb][2] = s.z; acc[fb][3] = s.w;
        *(uint2*)(aH + fm * ROW128 + fb * 32 + quad * 8) = cvt4hi(s);
    }
}

// ---------------- node MLP layer 1 (MFMA) ----------------
__global__ __launch_bounds__(256) void n1_kernel(
    const float* __restrict__ x, const float* __restrict__ agg,
    const u16* __restrict__ w1h, const u16* __restrict__ w1l, const float* __restrict__ b1,
    const u16* __restrict__ w2h, const u16* __restrict__ w2l, const float* __restrict__ b2,
    float* __restrict__ hout)
{
    __shared__ __align__(16) unsigned char smem[4][2560 + 16 * ROW128];
    const int tid = threadIdx.x, lane = tid & 63, wid = tid >> 6;
    const int quad = lane >> 4, fm = lane & 15;
    const int tile = blockIdx.x * 4 + wid;
    unsigned char* inH = smem[wid];
    unsigned char* inL = inH + 16 * ROW32;
    unsigned char* aH  = inH + 2560;
    const size_t base = (size_t)tile * 16 * NF;
    #pragma unroll
    for (int i = 0; i < 2; ++i) {
        const int flat = i * 64 + lane;
        const int node = flat >> 3, kq = flat & 7;
        const float4 xv = *(const float4*)&x[base + node * NF + kq * 4];
        const float4 av = *(const float4*)&agg[base + node * NF + kq * 4];
        const float4 s = {xv.x + av.x, xv.y + av.y, xv.z + av.z, xv.w + av.w};
        uint2 phi, plo;
        cvt4(s, phi, plo);
        *(uint2*)(inH + node * ROW32 + kq * 8) = phi;
        *(uint2*)(inL + node * ROW32 + kq * 8) = plo;
    }
    __syncthreads();
    vf4 acc[8];
    mfma_layer32_in(inH, inL, w1h, w1l, b1, lane, acc);
    __syncthreads();
    store_act_hi(aH, lane, acc);
    __syncthreads();
    mfma_layer128_act(aH, w2h, w2l, b2, lane, acc);
    const size_t ob = (size_t)tile * 16 * HD;
    #pragma unroll
    for (int fb = 0; fb < 8; ++fb) {
        const float4 o = {fmaxf(acc[fb][0], 0.0f), fmaxf(acc[fb][1], 0.0f),
                          fmaxf(acc[fb][2], 0.0f), fmaxf(acc[fb][3], 0.0f)};
        *(float4*)&hout[ob + fm * HD + fb * 16 + quad * 4] = o;
    }
}

// ---- node layer 2 + pooling + node-score head (MFMA, h2 never leaves the CU) ----
__global__ __launch_bounds__(256) void n2_kernel(
    const float* __restrict__ h, const float* __restrict__ agg,
    const u16* __restrict__ w1h, const u16* __restrict__ w1l, const float* __restrict__ b1,
    const u16* __restrict__ w2h, const u16* __restrict__ w2l, const float* __restrict__ b2,
    const u16* __restrict__ m1h, const u16* __restrict__ m1l, const float* __restrict__ nb1,
    const u16* __restrict__ m2h, const u16* __restrict__ m2l, const float* __restrict__ nb2,
    const float* __restrict__ nw3, const float* __restrict__ nb3,
    float* __restrict__ pooled, float* __restrict__ scores)
{
    __shared__ __align__(16) unsigned char smem[4][2 * 16 * ROW128];
    const int tid = threadIdx.x, lane = tid & 63, wid = tid >> 6;
    const int quad = lane >> 4, fm = lane & 15;
    const int tile = blockIdx.x * 4 + wid;
    unsigned char* aH = smem[wid];
    unsigned char* aL = aH + 16 * ROW128;
    const size_t base = (size_t)tile * 16 * HD;
    #pragma unroll
    for (int i = 0; i < 8; ++i) {
        const int flat = i * 64 + lane;
        const int node = flat >> 5, kq = flat & 31;
        const float4 hv = *(const float4*)&h[base + node * HD + kq * 4];
        const float4 av = *(const float4*)&agg[base + node * HD + kq * 4];
        const float4 s = {hv.x + av.x, hv.y + av.y, hv.z + av.z, hv.w + av.w};
        uint2 phi, plo;
        cvt4(s, phi, plo);
        *(uint2*)(aH + node * ROW128 + kq * 8) = phi;
        *(uint2*)(aL + node * ROW128 + kq * 8) = plo;
    }
    __syncthreads();
    vf4 acc[8];
    mfma_layer128_in(aH, aL, w1h, w1l, b1, lane, acc);   // consumes staged hi+lo
    __syncthreads();
    store_act_hi(aH, lane, acc);                          // aL dead from here on
    __syncthreads();
    mfma_layer128_act(aH, w2h, w2l, b2, lane, acc);
    __syncthreads();
    store_act_hi(aH, lane, acc);                          // acc now holds h2 (leaky'd)
    {
        const int g = tile >> 6;
        #pragma unroll
        for (int fb = 0; fb < 8; ++fb) {
            vf4 t = acc[fb];
            #pragma unroll
            for (int off = 1; off < 16; off <<= 1) {
                t[0] += __shfl_xor(t[0], off, 64);
                t[1] += __shfl_xor(t[1], off, 64);
                t[2] += __shfl_xor(t[2], off, 64);
                t[3] += __shfl_xor(t[3], off, 64);
            }
            #pragma unroll
            for (int r = 0; r < 4; ++r) {
                const int item = fb * 4 + r;
                if (fm == (item >> 1))
                    atomicAdd(&pooled[g * HD + fb * 16 + quad * 4 + r], t[r]);
            }
        }
    }
    __syncthreads();
    mfma_layer128_act(aH, m1h, m1l, nb1, lane, acc);
    __syncthreads();
    store_act_hi(aH, lane, acc);
    __syncthreads();
    mfma_layer128_act(aH, m2h, m2l, nb2, lane, acc);
    float v = 0.0f;
    #pragma unroll
    for (int fb = 0; fb < 8; ++fb) {
        const float4 w3v = *(const float4*)&nw3[fb * 16 + quad * 4];
        v += leakyf(acc[fb][0]) * w3v.x + leakyf(acc[fb][1]) * w3v.y
           + leakyf(acc[fb][2]) * w3v.z + leakyf(acc[fb][3]) * w3v.w;
    }
    v += __shfl_xor(v, 16, 64);
    v += __shfl_xor(v, 32, 64);
    if (lane < 16) {
        const int node = tile * 16 + fm;
        const float s = v + nb3[0];
        scores[(node & 63) * NPER + (node >> 6)] = 1.0f / (1.0f + expf(-s));
    }
}

// ---------------- action head: pooled mean -> MLP -> softmax ----------------
__global__ __launch_bounds__(128) void act_kernel(
    const float* __restrict__ pooled,
    const float* __restrict__ w1, const float* __restrict__ b1,
    const float* __restrict__ w2, const float* __restrict__ b2,
    float* __restrict__ out)
{
    __shared__ __align__(16) float p[HD];
    __shared__ float a1[HD];
    __shared__ float z[NACT];
    __shared__ float red2[2];
    const int g = blockIdx.x;
    const int tid = threadIdx.x;
    p[tid] = pooled[g * HD + tid] * (1.0f / NPER);
    __syncthreads();
    float acc = b1[tid];
    for (int k = 0; k < HD; ++k) acc = fmaf(p[k], w1[k * HD + tid], acc);
    a1[tid] = leakyf(acc);
    __syncthreads();
    if (tid < NACT) {
        float a2 = b2[tid];
        for (int k = 0; k < HD; ++k) a2 = fmaf(a1[k], w2[k * NACT + tid], a2);
        z[tid] = leakyf(a2);
    }
    __syncthreads();
    if (tid == 0) {
        float m = z[0];
        for (int i = 1; i < NACT; ++i) m = fmaxf(m, z[i]);
        red2[0] = m;
    }
    __syncthreads();
    if (tid < NACT) z[tid] = expf(z[tid] - red2[0]);
    __syncthreads();
    if (tid == 0) {
        float s = 0.0f;
        for (int i = 0; i < NACT; ++i) s += z[i];
        red2[1] = s;
    }
    __syncthreads();
    if (tid < NACT) out[g * NACT + tid] = z[tid] / red2[1];
}

extern "C" void kernel_launch(void* const* d_in, const int* in_sizes, int n_in,
                              void* d_out, int out_size, void* d_ws, size_t ws_size,
                              hipStream_t stream)
{
    const float* x    = (const float*)d_in[0];
    const int*   ei   = (const int*)d_in[1];     // int32
    const float* ea   = (const float*)d_in[2];
    const float* e1w  = (const float*)d_in[3];
    const float* e1b  = (const float*)d_in[4];
    const float* c1w1 = (const float*)d_in[5];
    const float* c1b1 = (const float*)d_in[6];
    const float* c1w2 = (const float*)d_in[7];
    const float* c1b2 = (const float*)d_in[8];
    const float* e2w  = (const float*)d_in[9];
    const float* e2b  = (const float*)d_in[10];
    const float* c2w1 = (const float*)d_in[11];
    const float* c2b1 = (const float*)d_in[12];
    const float* c2w2 = (const float*)d_in[13];
    const float* c2b2 = (const float*)d_in[14];
    const float* aw1  = (const float*)d_in[15];
    const float* ab1  = (const float*)d_in[16];
    const float* aw2  = (const float*)d_in[17];
    const float* ab2  = (const float*)d_in[18];
    const float* nw1  = (const float*)d_in[19];
    const float* nb1  = (const float*)d_in[20];
    const float* nw2  = (const float*)d_in[21];
    const float* nb2  = (const float*)d_in[22];
    const float* nw3  = (const float*)d_in[23];
    const float* nb3  = (const float*)d_in[24];

    float* out = (float*)d_out;
    char*  ws  = (char*)d_ws;
    const size_t MB = 1024 * 1024;
    float* h      = (float*)(ws);
    float* agg2   = (float*)(ws + 32  * MB);
    int*   seidx  = (int*)  (ws + 32  * MB);     // dead before e2_agg writes agg2
    float* sea    = (float*)(ws + 64  * MB);
    float* agg1   = (float*)(ws + 128 * MB);
    float* pooled = (float*)(ws + 136 * MB);
    u16*   pw     = (u16*)  (ws + 136 * MB + 64 * 1024);
    int*   cnt    = (int*)  (ws + 137 * MB);
    int*   fill   = (int*)  (ws + 137 * MB + 256 * 1024);
    int*   rs     = (int*)  (ws + 139 * MB);
    int*   ssrc   = (int*)  (ws + 140 * MB);

    u16* p_c1w1 = pw;
    u16* p_c1w2 = pw + 1 * 32768;
    u16* p_c2w1 = pw + 2 * 32768;
    u16* p_c2w2 = pw + 3 * 32768;
    u16* p_nw1  = pw + 4 * 32768;
    u16* p_nw2  = pw + 5 * 32768;

    hipMemsetAsync(cnt,    0, 2 * NNODES * sizeof(int), stream);
    hipMemsetAsync(pooled, 0, (size_t)NB * HD * sizeof(float), stream);

    pack_all_kernel<<<336, 256, 0, stream>>>(c1w1, c1w2, c2w1, c2w2, nw1, nw2, pw);

    hist_kernel<<<NEDGES / 256, 256, 0, stream>>>(ei, cnt);
    scan_kernel<<<1, 1024, 0, stream>>>(cnt, rs);
    scatter_kernel<<<NEDGES / 256, 256, 0, stream>>>(ei, rs, fill, ssrc, seidx);
    permute_kernel<<<NEDGES / 64, 256, 0, stream>>>(seidx, ea, sea);

    e1_agg_kernel<<<NNODES / 4, 256, 0, stream>>>(x, rs, ssrc, sea, e1w, e1b, agg1);
    n1_kernel<<<NNODES / 64, 256, 0, stream>>>(x, agg1,
                                               p_c1w1, p_c1w1 + 16384, c1b1,
                                               p_c1w2, p_c1w2 + 16384, c1b2, h);
    e2_agg_kernel<<<NNODES / 4, 256, 0, stream>>>(h, rs, ssrc, sea, e2w, e2b, agg2);
    n2_kernel<<<NNODES / 64, 256, 0, stream>>>(h, agg2,
                                               p_c2w1, p_c2w1 + 16384, c2b1,
                                               p_c2w2, p_c2w2 + 16384, c2b2,
                                               p_nw1,  p_nw1  + 16384, nb1,
                                               p_nw2,  p_nw2  + 16384, nb2,
                                               nw3, nb3, pooled, out + NB * NACT);
    act_kernel<<<NB, 128, 0, stream>>>(pooled, aw1, ab1, aw2, ab2, out);
}

// Round 9
// 578.483 us; speedup vs baseline: 1.4894x; 1.0023x over previous
//
#include <hip/hip_runtime.h>
#include <math.h>

#define NNODES 65536
#define NEDGES 1048576
#define NF 32
#define EF 16
#define HD 128
#define NACT 10
#define NB 64
#define NPER 1024

typedef unsigned short u16;
typedef float  vf2  __attribute__((ext_vector_type(2)));
typedef float  vf4  __attribute__((ext_vector_type(4)));
typedef __bf16 vbf8 __attribute__((ext_vector_type(8)));
#define BC8(v) __builtin_bit_cast(vbf8, v)
#define WB() __builtin_amdgcn_wave_barrier()   // compile-time phase fence, no HW cost

__device__ __forceinline__ float leakyf(float v) { return v > 0.0f ? v : 0.01f * v; }
__device__ __forceinline__ vf2 fma2(vf2 a, vf2 b, vf2 c) { return __builtin_elementwise_fma(a, b, c); }
__device__ __forceinline__ vf2 max2(vf2 a, vf2 b) { return __builtin_elementwise_max(a, b); }
__device__ __forceinline__ vf2 splat2(float s) { vf2 r = {s, s}; return r; }

__device__ __forceinline__ u16 f2bf(float x) {
    unsigned u = __float_as_uint(x);
    return (u16)((u + 0x7FFFu + ((u >> 16) & 1u)) >> 16);
}
__device__ __forceinline__ float bf2f(u16 h) { return __uint_as_float(((unsigned)h) << 16); }

// split f32x4 into bf16-hi and bf16-lo packed pairs (hi + lo ~= full f32 precision)
__device__ __forceinline__ void cvt4(const float4 s, uint2& hi, uint2& lo) {
    const u16 h0 = f2bf(s.x), h1 = f2bf(s.y), h2 = f2bf(s.z), h3 = f2bf(s.w);
    hi = make_uint2((unsigned)h0 | ((unsigned)h1 << 16), (unsigned)h2 | ((unsigned)h3 << 16));
    const u16 l0 = f2bf(s.x - bf2f(h0)), l1 = f2bf(s.y - bf2f(h1));
    const u16 l2 = f2bf(s.z - bf2f(h2)), l3 = f2bf(s.w - bf2f(h3));
    lo = make_uint2((unsigned)l0 | ((unsigned)l1 << 16), (unsigned)l2 | ((unsigned)l3 << 16));
}
// hi-only variant (internal activations)
__device__ __forceinline__ uint2 cvt4hi(const float4 s) {
    const u16 h0 = f2bf(s.x), h1 = f2bf(s.y), h2 = f2bf(s.z), h3 = f2bf(s.w);
    return make_uint2((unsigned)h0 | ((unsigned)h1 << 16), (unsigned)h2 | ((unsigned)h3 << 16));
}

// ---------------- CSR build: histogram -> scan -> scatter(idx) -> gather-permute ----------------
__global__ __launch_bounds__(256) void hist_kernel(const int* __restrict__ ei, int* __restrict__ cnt)
{
    const int i = blockIdx.x * 256 + threadIdx.x;
    if (i < NEDGES) atomicAdd(&cnt[ei[NEDGES + i]], 1);
}

__global__ __launch_bounds__(1024) void scan_kernel(const int* __restrict__ cnt, int* __restrict__ rs)
{
    __shared__ int s[1024];
    const int t = threadIdx.x;
    int loc[64];
    int tot = 0;
    const int4* c4 = (const int4*)(cnt + t * 64);
    #pragma unroll
    for (int j = 0; j < 16; ++j) {
        const int4 v = c4[j];
        loc[4*j+0] = v.x; loc[4*j+1] = v.y; loc[4*j+2] = v.z; loc[4*j+3] = v.w;
        tot += v.x + v.y + v.z + v.w;
    }
    s[t] = tot;
    __syncthreads();
    for (int off = 1; off < 1024; off <<= 1) {
        const int v = (t >= off) ? s[t - off] : 0;
        __syncthreads();
        s[t] += v;
        __syncthreads();
    }
    int run = s[t] - tot;
    #pragma unroll
    for (int j = 0; j < 64; ++j) { rs[t * 64 + j] = run; run += loc[j]; }
    if (t == 0) rs[NNODES] = NEDGES;
}

__global__ __launch_bounds__(256) void scatter_kernel(
    const int* __restrict__ ei, const int* __restrict__ rs, int* __restrict__ fill,
    int* __restrict__ ssrc, int* __restrict__ seidx)
{
    const int i = blockIdx.x * 256 + threadIdx.x;
    if (i < NEDGES) {
        const int d = ei[NEDGES + i];
        const int pos = rs[d] + atomicAdd(&fill[d], 1);
        ssrc[pos]  = ei[i];
        seidx[pos] = i;
    }
}

__global__ __launch_bounds__(256) void permute_kernel(
    const int* __restrict__ seidx, const float* __restrict__ ea, float* __restrict__ sea)
{
    const int t = blockIdx.x * 256 + threadIdx.x;
    const int e = t >> 2, part = t & 3;
    const int idx = seidx[e];
    ((float4*)sea)[(size_t)e * 4 + part] = ((const float4*)ea)[(size_t)idx * 4 + part];
}

// ---------------- weight packing (all 6 matrices, one launch) ----------------
__global__ __launch_bounds__(256) void pack_all_kernel(
    const float* __restrict__ w0, const float* __restrict__ w1, const float* __restrict__ w2,
    const float* __restrict__ w3, const float* __restrict__ w4, const float* __restrict__ w5,
    u16* __restrict__ pw)
{
    const int bid = blockIdx.x;
    const float* W; int KB, seg, sbase;
    if (bid < 16) { W = w0; KB = 1; seg = 0; sbase = 0; }
    else {
        const int i = (bid - 16) >> 6;
        seg = i + 1; sbase = 16 + i * 64; KB = 4;
        W = (i == 0) ? w1 : (i == 1) ? w2 : (i == 2) ? w3 : (i == 3) ? w4 : w5;
    }
    const int t = (bid - sbase) * 256 + threadIdx.x;
    const int j = t & 7, lane = (t >> 3) & 63, rest = t >> 9;
    const int kb = rest % KB, fb = rest / KB;
    if (fb >= 8) return;
    const int k = kb * 32 + (lane >> 4) * 8 + j;
    const int f = fb * 16 + (lane & 15);
    const float val = W[k * HD + f];
    const u16 h = f2bf(val);
    u16* dst = pw + seg * 32768;
    dst[t] = h;
    dst[16384 + t] = f2bf(val - bf2f(h));
}

// ---------------- edge layer 1 (gather): quarter-chains, feature pairs, pk_fma ----------------
__global__ __launch_bounds__(256) void e1_agg_kernel(
    const float* __restrict__ x, const int* __restrict__ rs,
    const int* __restrict__ ssrc, const float* __restrict__ sea,
    const float* __restrict__ w, const float* __restrict__ b, float* __restrict__ agg)
{
    const int tid  = threadIdx.x;
    const int lane = tid & 63;
    const int p    = lane & 15;          // feature pair: f = 2p, 2p+1
    const int q    = lane >> 4;          // edge chain 0..3
    const int node = blockIdx.x * 4 + (tid >> 6);
    vf2 wr[EF];
    #pragma unroll
    for (int k = 0; k < EF; ++k) wr[k] = *(const vf2*)&w[k * NF + p * 2];
    const vf2 bias = *(const vf2*)&b[p * 2];
    const int beg = rs[node], end = rs[node + 1];
    vf2 acc = {0.0f, 0.0f};
    for (int e = beg + q; e < end; e += 4) {
        const int sA = ssrc[e];
        const float4* pA = (const float4*)sea + (size_t)e * 4;
        const float4 A0 = pA[0], A1 = pA[1], A2 = pA[2], A3 = pA[3];
        const vf2 xv = *(const vf2*)((const char*)x + (((unsigned)sA << 7) + (unsigned)p * 8));
        vf2 m = bias;
        m = fma2(splat2(A0.x), wr[0],  m); m = fma2(splat2(A0.y), wr[1],  m);
        m = fma2(splat2(A0.z), wr[2],  m); m = fma2(splat2(A0.w), wr[3],  m);
        m = fma2(splat2(A1.x), wr[4],  m); m = fma2(splat2(A1.y), wr[5],  m);
        m = fma2(splat2(A1.z), wr[6],  m); m = fma2(splat2(A1.w), wr[7],  m);
        m = fma2(splat2(A2.x), wr[8],  m); m = fma2(splat2(A2.y), wr[9],  m);
        m = fma2(splat2(A2.z), wr[10], m); m = fma2(splat2(A2.w), wr[11], m);
        m = fma2(splat2(A3.x), wr[12], m); m = fma2(splat2(A3.y), wr[13], m);
        m = fma2(splat2(A3.z), wr[14], m); m = fma2(splat2(A3.w), wr[15], m);
        acc += max2(xv + m, splat2(0.0f));
    }
    acc[0] += __shfl_xor(acc[0], 16, 64); acc[1] += __shfl_xor(acc[1], 16, 64);
    acc[0] += __shfl_xor(acc[0], 32, 64); acc[1] += __shfl_xor(acc[1], 32, 64);
    if (lane < 16) *(vf2*)&agg[(size_t)node * NF + p * 2] = acc;
}

// ---------------- edge layer 2 (gather): scalar-uniform sea/ssrc + pk_fma ----------------
__global__ __launch_bounds__(256) void e2_agg_kernel(
    const float* __restrict__ h, const int* __restrict__ rs,
    const int* __restrict__ ssrc, const float* __restrict__ sea,
    const float* __restrict__ w, const float* __restrict__ b, float* __restrict__ agg)
{
    const int tid  = threadIdx.x;
    const int lane = tid & 63;
    const unsigned foff = (unsigned)lane * 8;    // byte offset of feature pair
    const int node = blockIdx.x * 4 + (tid >> 6);
    vf2 wr[EF];
    #pragma unroll
    for (int k = 0; k < EF; ++k) wr[k] = *(const vf2*)&w[k * HD + lane * 2];
    const vf2 bias = *(const vf2*)&b[lane * 2];
    const int beg = __builtin_amdgcn_readfirstlane(rs[node]);
    const int end = __builtin_amdgcn_readfirstlane(rs[node + 1]);
    vf2 acc = {0.0f, 0.0f};
    int e = beg;
    for (; e + 2 <= end; e += 2) {
        const int sA = ssrc[e];                  // uniform -> s_load
        const int sB = ssrc[e + 1];
        const vf2 hA = *(const vf2*)((const char*)h + (((unsigned)sA << 9) + foff));
        const vf2 hB = *(const vf2*)((const char*)h + (((unsigned)sB << 9) + foff));
        const float* aA = &sea[(size_t)e * EF];  // uniform -> s_load_dwordx16
        const float* aB = aA + EF;
        vf2 mA = bias, mB = bias;
        #pragma unroll
        for (int k = 0; k < EF; ++k) {
            mA = fma2(splat2(aA[k]), wr[k], mA);
            mB = fma2(splat2(aB[k]), wr[k], mB);
        }
        acc += max2(hA + mA, splat2(0.0f));
        acc += max2(hB + mB, splat2(0.0f));
    }
    if (e < end) {
        const int sA = ssrc[e];
        const vf2 hA = *(const vf2*)((const char*)h + (((unsigned)sA << 9) + foff));
        const float* aA = &sea[(size_t)e * EF];
        vf2 mA = bias;
        #pragma unroll
        for (int k = 0; k < EF; ++k) mA = fma2(splat2(aA[k]), wr[k], mA);
        acc += max2(hA + mA, splat2(0.0f));
    }
    *(vf2*)&agg[(size_t)node * HD + lane * 2] = acc;
}

// ---------------- MFMA node-GEMM building blocks ----------------
#define ROW128 272   // 128 bf16 = 256 B + 16 pad
#define ROW32  80    // 32 bf16 = 64 B + 16 pad

// layer consuming STAGED input (hi+lo B): 3 MFMAs per (fb,kb)
__device__ __forceinline__ void mfma_layer128_in(
    const unsigned char* __restrict__ aH, const unsigned char* __restrict__ aL,
    const u16* __restrict__ wH, const u16* __restrict__ wL,
    const float* __restrict__ bias, int lane, vf4* __restrict__ acc)
{
    const int quad = lane >> 4, fm = lane & 15;
    int4 Bh[4], Bl[4];
    #pragma unroll
    for (int kb = 0; kb < 4; ++kb) {
        Bh[kb] = *(const int4*)(aH + fm * ROW128 + kb * 64 + quad * 16);
        Bl[kb] = *(const int4*)(aL + fm * ROW128 + kb * 64 + quad * 16);
    }
    #pragma unroll
    for (int fb = 0; fb < 8; ++fb) {
        const float4 bv = *(const float4*)&bias[fb * 16 + quad * 4];
        vf4 a = {bv.x, bv.y, bv.z, bv.w};
        #pragma unroll
        for (int kb = 0; kb < 4; ++kb) {
            const int4 wh = *(const int4*)(wH + ((fb * 4 + kb) * 64 + lane) * 8);
            const int4 wl = *(const int4*)(wL + ((fb * 4 + kb) * 64 + lane) * 8);
            a = __builtin_amdgcn_mfma_f32_16x16x32_bf16(BC8(wh), BC8(Bl[kb]), a, 0, 0, 0);
            a = __builtin_amdgcn_mfma_f32_16x16x32_bf16(BC8(wl), BC8(Bh[kb]), a, 0, 0, 0);
            a = __builtin_amdgcn_mfma_f32_16x16x32_bf16(BC8(wh), BC8(Bh[kb]), a, 0, 0, 0);
        }
        acc[fb] = a;
    }
}

// layer consuming internal ACTIVATIONS (hi-only B): 2 MFMAs per (fb,kb)
__device__ __forceinline__ void mfma_layer128_act(
    const unsigned char* __restrict__ aH,
    const u16* __restrict__ wH, const u16* __restrict__ wL,
    const float* __restrict__ bias, int lane, vf4* __restrict__ acc)
{
    const int quad = lane >> 4, fm = lane & 15;
    int4 Bh[4];
    #pragma unroll
    for (int kb = 0; kb < 4; ++kb)
        Bh[kb] = *(const int4*)(aH + fm * ROW128 + kb * 64 + quad * 16);
    #pragma unroll
    for (int fb = 0; fb < 8; ++fb) {
        const float4 bv = *(const float4*)&bias[fb * 16 + quad * 4];
        vf4 a = {bv.x, bv.y, bv.z, bv.w};
        #pragma unroll
        for (int kb = 0; kb < 4; ++kb) {
            const int4 wh = *(const int4*)(wH + ((fb * 4 + kb) * 64 + lane) * 8);
            const int4 wl = *(const int4*)(wL + ((fb * 4 + kb) * 64 + lane) * 8);
            a = __builtin_amdgcn_mfma_f32_16x16x32_bf16(BC8(wl), BC8(Bh[kb]), a, 0, 0, 0);
            a = __builtin_amdgcn_mfma_f32_16x16x32_bf16(BC8(wh), BC8(Bh[kb]), a, 0, 0, 0);
        }
        acc[fb] = a;
    }
}

__device__ __forceinline__ void mfma_layer32_in(
    const unsigned char* __restrict__ aH, const unsigned char* __restrict__ aL,
    const u16* __restrict__ wH, const u16* __restrict__ wL,
    const float* __restrict__ bias, int lane, vf4* __restrict__ acc)
{
    const int quad = lane >> 4, fm = lane & 15;
    const int4 Bh = *(const int4*)(aH + fm * ROW32 + quad * 16);
    const int4 Bl = *(const int4*)(aL + fm * ROW32 + quad * 16);
    #pragma unroll
    for (int fb = 0; fb < 8; ++fb) {
        const float4 bv = *(const float4*)&bias[fb * 16 + quad * 4];
        vf4 a = {bv.x, bv.y, bv.z, bv.w};
        const int4 wh = *(const int4*)(wH + (fb * 64 + lane) * 8);
        const int4 wl = *(const int4*)(wL + (fb * 64 + lane) * 8);
        a = __builtin_amdgcn_mfma_f32_16x16x32_bf16(BC8(wh), BC8(Bl), a, 0, 0, 0);
        a = __builtin_amdgcn_mfma_f32_16x16x32_bf16(BC8(wl), BC8(Bh), a, 0, 0, 0);
        a = __builtin_amdgcn_mfma_f32_16x16x32_bf16(BC8(wh), BC8(Bh), a, 0, 0, 0);
        acc[fb] = a;
    }
}

// apply leaky, write hi-only activations to LDS (acc updated to post-activation values)
__device__ __forceinline__ void store_act_hi(
    unsigned char* __restrict__ aH, int lane, vf4* __restrict__ acc)
{
    const int quad = lane >> 4, fm = lane & 15;
    #pragma unroll
    for (int fb = 0; fb < 8; ++fb) {
        const float4 s = {leakyf(acc[fb][0]), leakyf(acc[fb][1]), leakyf(acc[fb][2]), leakyf(acc[fb][3])};
        acc[fb][0] = s.x; acc[fb][1] = s.y; acc[fb][2] = s.z; acc[fb][3] = s.w;
        *(uint2*)(aH + fm * ROW128 + fb * 32 + quad * 8) = cvt4hi(s);
    }
}

// ---------------- node MLP layer 1 (MFMA, wave-private slab, NO block barriers) ----------------
__global__ __launch_bounds__(256) void n1_kernel(
    const float* __restrict__ x, const float* __restrict__ agg,
    const u16* __restrict__ w1h, const u16* __restrict__ w1l, const float* __restrict__ b1,
    const u16* __restrict__ w2h, const u16* __restrict__ w2l, const float* __restrict__ b2,
    float* __restrict__ hout)
{
    __shared__ __align__(16) unsigned char smem[4][2560 + 16 * ROW128];
    const int tid = threadIdx.x, lane = tid & 63, wid = tid >> 6;
    const int quad = lane >> 4, fm = lane & 15;
    const int tile = blockIdx.x * 4 + wid;
    unsigned char* inH = smem[wid];
    unsigned char* inL = inH + 16 * ROW32;
    unsigned char* aH  = inH + 2560;
    const size_t base = (size_t)tile * 16 * NF;
    #pragma unroll
    for (int i = 0; i < 2; ++i) {
        const int flat = i * 64 + lane;
        const int node = flat >> 3, kq = flat & 7;
        const float4 xv = *(const float4*)&x[base + node * NF + kq * 4];
        const float4 av = *(const float4*)&agg[base + node * NF + kq * 4];
        const float4 s = {xv.x + av.x, xv.y + av.y, xv.z + av.z, xv.w + av.w};
        uint2 phi, plo;
        cvt4(s, phi, plo);
        *(uint2*)(inH + node * ROW32 + kq * 8) = phi;
        *(uint2*)(inL + node * ROW32 + kq * 8) = plo;
    }
    WB();
    vf4 acc[8];
    mfma_layer32_in(inH, inL, w1h, w1l, b1, lane, acc);
    WB();
    store_act_hi(aH, lane, acc);
    WB();
    mfma_layer128_act(aH, w2h, w2l, b2, lane, acc);
    const size_t ob = (size_t)tile * 16 * HD;
    #pragma unroll
    for (int fb = 0; fb < 8; ++fb) {
        const float4 o = {fmaxf(acc[fb][0], 0.0f), fmaxf(acc[fb][1], 0.0f),
                          fmaxf(acc[fb][2], 0.0f), fmaxf(acc[fb][3], 0.0f)};
        *(float4*)&hout[ob + fm * HD + fb * 16 + quad * 4] = o;
    }
}

// ---- node layer 2 + pooling + node-score head (MFMA, wave-private slab, NO block barriers) ----
__global__ __launch_bounds__(256) void n2_kernel(
    const float* __restrict__ h, const float* __restrict__ agg,
    const u16* __restrict__ w1h, const u16* __restrict__ w1l, const float* __restrict__ b1,
    const u16* __restrict__ w2h, const u16* __restrict__ w2l, const float* __restrict__ b2,
    const u16* __restrict__ m1h, const u16* __restrict__ m1l, const float* __restrict__ nb1,
    const u16* __restrict__ m2h, const u16* __restrict__ m2l, const float* __restrict__ nb2,
    const float* __restrict__ nw3, const float* __restrict__ nb3,
    float* __restrict__ pooled, float* __restrict__ scores)
{
    __shared__ __align__(16) unsigned char smem[4][2 * 16 * ROW128];
    const int tid = threadIdx.x, lane = tid & 63, wid = tid >> 6;
    const int quad = lane >> 4, fm = lane & 15;
    const int tile = blockIdx.x * 4 + wid;
    unsigned char* aH = smem[wid];
    unsigned char* aL = aH + 16 * ROW128;
    const size_t base = (size_t)tile * 16 * HD;
    #pragma unroll
    for (int i = 0; i < 8; ++i) {
        const int flat = i * 64 + lane;
        const int node = flat >> 5, kq = flat & 31;
        const float4 hv = *(const float4*)&h[base + node * HD + kq * 4];
        const float4 av = *(const float4*)&agg[base + node * HD + kq * 4];
        const float4 s = {hv.x + av.x, hv.y + av.y, hv.z + av.z, hv.w + av.w};
        uint2 phi, plo;
        cvt4(s, phi, plo);
        *(uint2*)(aH + node * ROW128 + kq * 8) = phi;
        *(uint2*)(aL + node * ROW128 + kq * 8) = plo;
    }
    WB();
    vf4 acc[8];
    mfma_layer128_in(aH, aL, w1h, w1l, b1, lane, acc);   // consumes staged hi+lo
    WB();
    store_act_hi(aH, lane, acc);                          // aL dead from here on
    WB();
    mfma_layer128_act(aH, w2h, w2l, b2, lane, acc);
    WB();
    store_act_hi(aH, lane, acc);                          // acc now holds h2 (leaky'd)
    {
        const int g = tile >> 6;
        #pragma unroll
        for (int fb = 0; fb < 8; ++fb) {
            vf4 t = acc[fb];
            #pragma unroll
            for (int off = 1; off < 16; off <<= 1) {
                t[0] += __shfl_xor(t[0], off, 64);
                t[1] += __shfl_xor(t[1], off, 64);
                t[2] += __shfl_xor(t[2], off, 64);
                t[3] += __shfl_xor(t[3], off, 64);
            }
            #pragma unroll
            for (int r = 0; r < 4; ++r) {
                const int item = fb * 4 + r;
                if (fm == (item >> 1))
                    atomicAdd(&pooled[g * HD + fb * 16 + quad * 4 + r], t[r]);
            }
        }
    }
    WB();
    mfma_layer128_act(aH, m1h, m1l, nb1, lane, acc);
    WB();
    store_act_hi(aH, lane, acc);
    WB();
    mfma_layer128_act(aH, m2h, m2l, nb2, lane, acc);
    float v = 0.0f;
    #pragma unroll
    for (int fb = 0; fb < 8; ++fb) {
        const float4 w3v = *(const float4*)&nw3[fb * 16 + quad * 4];
        v += leakyf(acc[fb][0]) * w3v.x + leakyf(acc[fb][1]) * w3v.y
           + leakyf(acc[fb][2]) * w3v.z + leakyf(acc[fb][3]) * w3v.w;
    }
    v += __shfl_xor(v, 16, 64);
    v += __shfl_xor(v, 32, 64);
    if (lane < 16) {
        const int node = tile * 16 + fm;
        const float s = v + nb3[0];
        scores[(node & 63) * NPER + (node >> 6)] = 1.0f / (1.0f + expf(-s));
    }
}

// ---------------- action head: pooled mean -> MLP -> softmax ----------------
__global__ __launch_bounds__(128) void act_kernel(
    const float* __restrict__ pooled,
    const float* __restrict__ w1, const float* __restrict__ b1,
    const float* __restrict__ w2, const float* __restrict__ b2,
    float* __restrict__ out)
{
    __shared__ __align__(16) float p[HD];
    __shared__ float a1[HD];
    __shared__ float z[NACT];
    __shared__ float red2[2];
    const int g = blockIdx.x;
    const int tid = threadIdx.x;
    p[tid] = pooled[g * HD + tid] * (1.0f / NPER);
    __syncthreads();
    float acc = b1[tid];
    for (int k = 0; k < HD; ++k) acc = fmaf(p[k], w1[k * HD + tid], acc);
    a1[tid] = leakyf(acc);
    __syncthreads();
    if (tid < NACT) {
        float a2 = b2[tid];
        for (int k = 0; k < HD; ++k) a2 = fmaf(a1[k], w2[k * NACT + tid], a2);
        z[tid] = leakyf(a2);
    }
    __syncthreads();
    if (tid == 0) {
        float m = z[0];
        for (int i = 1; i < NACT; ++i) m = fmaxf(m, z[i]);
        red2[0] = m;
    }
    __syncthreads();
    if (tid < NACT) z[tid] = expf(z[tid] - red2[0]);
    __syncthreads();
    if (tid == 0) {
        float s = 0.0f;
        for (int i = 0; i < NACT; ++i) s += z[i];
        red2[1] = s;
    }
    __syncthreads();
    if (tid < NACT) out[g * NACT + tid] = z[tid] / red2[1];
}

extern "C" void kernel_launch(void* const* d_in, const int* in_sizes, int n_in,
                              void* d_out, int out_size, void* d_ws, size_t ws_size,
                              hipStream_t stream)
{
    const float* x    = (const float*)d_in[0];
    const int*   ei   = (const int*)d_in[1];     // int32
    const float* ea   = (const float*)d_in[2];
    const float* e1w  = (const float*)d_in[3];
    const float* e1b  = (const float*)d_in[4];
    const float* c1w1 = (const float*)d_in[5];
    const float* c1b1 = (const float*)d_in[6];
    const float* c1w2 = (const float*)d_in[7];
    const float* c1b2 = (const float*)d_in[8];
    const float* e2w  = (const float*)d_in[9];
    const float* e2b  = (const float*)d_in[10];
    const float* c2w1 = (const float*)d_in[11];
    const float* c2b1 = (const float*)d_in[12];
    const float* c2w2 = (const float*)d_in[13];
    const float* c2b2 = (const float*)d_in[14];
    const float* aw1  = (const float*)d_in[15];
    const float* ab1  = (const float*)d_in[16];
    const float* aw2  = (const float*)d_in[17];
    const float* ab2  = (const float*)d_in[18];
    const float* nw1  = (const float*)d_in[19];
    const float* nb1  = (const float*)d_in[20];
    const float* nw2  = (const float*)d_in[21];
    const float* nb2  = (const float*)d_in[22];
    const float* nw3  = (const float*)d_in[23];
    const float* nb3  = (const float*)d_in[24];

    float* out = (float*)d_out;
    char*  ws  = (char*)d_ws;
    const size_t MB = 1024 * 1024;
    float* h      = (float*)(ws);
    float* agg2   = (float*)(ws + 32  * MB);
    int*   seidx  = (int*)  (ws + 32  * MB);     // dead before e2_agg writes agg2
    float* sea    = (float*)(ws + 64  * MB);
    float* agg1   = (float*)(ws + 128 * MB);
    float* pooled = (float*)(ws + 136 * MB);
    u16*   pw     = (u16*)  (ws + 136 * MB + 64 * 1024);
    int*   cnt    = (int*)  (ws + 137 * MB);
    int*   fill   = (int*)  (ws + 137 * MB + 256 * 1024);
    int*   rs     = (int*)  (ws + 139 * MB);
    int*   ssrc   = (int*)  (ws + 140 * MB);

    u16* p_c1w1 = pw;
    u16* p_c1w2 = pw + 1 * 32768;
    u16* p_c2w1 = pw + 2 * 32768;
    u16* p_c2w2 = pw + 3 * 32768;
    u16* p_nw1  = pw + 4 * 32768;
    u16* p_nw2  = pw + 5 * 32768;

    hipMemsetAsync(cnt,    0, 2 * NNODES * sizeof(int), stream);
    hipMemsetAsync(pooled, 0, (size_t)NB * HD * sizeof(float), stream);

    pack_all_kernel<<<336, 256, 0, stream>>>(c1w1, c1w2, c2w1, c2w2, nw1, nw2, pw);

    hist_kernel<<<NEDGES / 256, 256, 0, stream>>>(ei, cnt);
    scan_kernel<<<1, 1024, 0, stream>>>(cnt, rs);
    scatter_kernel<<<NEDGES / 256, 256, 0, stream>>>(ei, rs, fill, ssrc, seidx);
    permute_kernel<<<NEDGES / 64, 256, 0, stream>>>(seidx, ea, sea);

    e1_agg_kernel<<<NNODES / 4, 256, 0, stream>>>(x, rs, ssrc, sea, e1w, e1b, agg1);
    n1_kernel<<<NNODES / 64, 256, 0, stream>>>(x, agg1,
                                               p_c1w1, p_c1w1 + 16384, c1b1,
                                               p_c1w2, p_c1w2 + 16384, c1b2, h);
    e2_agg_kernel<<<NNODES / 4, 256, 0, stream>>>(h, rs, ssrc, sea, e2w, e2b, agg2);
    n2_kernel<<<NNODES / 64, 256, 0, stream>>>(h, agg2,
                                               p_c2w1, p_c2w1 + 16384, c2b1,
                                               p_c2w2, p_c2w2 + 16384, c2b2,
                                               p_nw1,  p_nw1  + 16384, nb1,
                                               p_nw2,  p_nw2  + 16384, nb2,
                                               nw3, nb3, pooled, out + NB * NACT);
    act_kernel<<<NB, 128, 0, stream>>>(pooled, aw1, ab1, aw2, ab2, out);
}